// Round 3
// baseline (257.817 us; speedup 1.0000x reference)
//
#include <hip/hip_runtime.h>
#include <math.h>

#define N_ 4096
#define D_ 64
#define NC_ 1000
#define KQ_ 8192
#define VCOLS 9192          // NC + KQ real columns
#define VPAD  9216          // 72*128 padded
#define NCB   72
#define PCH   73            // 72 gemm chunks + 1 sup chunk
#define TEMP_INV 20.0f
#define M0 20.25f           // fixed softmax reference for gemm chunks (dots <= 1)

// workspace layout (float offsets)
#define WS_F     0
#define WS_CENT  (WS_F + N_*D_)
#define WS_MU    (WS_CENT + NC_*D_)
#define WS_CNT   (WS_MU + D_)
#define WS_ACC   (WS_CNT + NC_)
#define WS_SUPM  (WS_ACC + 16)
#define WS_PSUP  (WS_SUPM + N_)
#define WS_PCENT (WS_PSUP + N_)
#define WS_PS    (WS_PCENT + N_)
#define WS_BBF   (WS_PS + N_*PCH)         // ushort[VPAD*64]
#define A_CENUM 0
#define A_CEDEN 1
#define A_CSUM  2
#define A_ISUM  3
#define A_SW    4
#define A_SB    5
#define A_IMIN  6

typedef __attribute__((ext_vector_type(8))) short short8_t;
typedef __attribute__((ext_vector_type(4))) float f32x4;

__device__ __forceinline__ ushort f2bf(float x) {
    union { float f; unsigned u; } v; v.f = x;
    unsigned r = (v.u + 0x7FFFu + ((v.u >> 16) & 1u)) >> 16;
    return (ushort)r;
}

__global__ __launch_bounds__(256) void k_init(float* ws) {
    int t = blockIdx.x * 256 + threadIdx.x;
    if (t < NC_) ws[WS_CNT + t] = 0.0f;
    if (t < D_)  ws[WS_MU + t] = 0.0f;
    if (t < 8)   ws[WS_ACC + t] = 0.0f;
    if (t == 0)  ((unsigned*)ws)[WS_ACC + A_IMIN] = 0x7F800000u; // +inf
}

// merged prep: norm_f rows (blocks 0..1023), norm_c cols (1024..1027),
// queue-tail bf16 (1028..2057)
__global__ __launch_bounds__(256) void k_prep(const float* __restrict__ feats,
                                              const float* __restrict__ C,
                                              const float* __restrict__ queue,
                                              float* __restrict__ f,
                                              float* __restrict__ cent,
                                              ushort* __restrict__ B) {
    int b = blockIdx.x;
    if (b < 1024) {
        int row  = b * 4 + (threadIdx.x >> 6);
        int lane = threadIdx.x & 63;
        float x = feats[row * D_ + lane];
        float ss = x * x;
        #pragma unroll
        for (int m = 32; m >= 1; m >>= 1) ss += __shfl_xor(ss, m, 64);
        float y = x / fmaxf(sqrtf(ss), 1e-12f);
        f[row * D_ + lane] = y;
        B[(size_t)(NC_ + row) * D_ + lane] = f2bf(y);
    } else if (b < 1028) {
        int c = (b - 1024) * 256 + threadIdx.x;
        if (c >= NC_) return;
        float v[D_];
        float ss = 0.0f;
        #pragma unroll
        for (int d = 0; d < D_; ++d) { float x = C[d * NC_ + c]; v[d] = x; ss += x * x; }
        float inv = 1.0f / fmaxf(sqrtf(ss), 1e-12f);
        #pragma unroll
        for (int d = 0; d < D_; ++d) {
            float y = v[d] * inv;
            cent[c * D_ + d] = y;
            B[(size_t)c * D_ + d] = f2bf(y);
        }
    } else {
        int t = (b - 1028) * 256 + threadIdx.x;   // over (4096+24)*64
        if (t >= (KQ_ - N_ + 24) * D_) return;
        int r = t >> 6, d = t & 63;
        ushort o = 0;
        if (r < KQ_ - N_) o = f2bf(queue[(size_t)(N_ + r) * D_ + d]);
        B[(size_t)(NC_ + N_ + r) * D_ + d] = o;
    }
}

// mu_sum, cls_cnt, S_W
__global__ __launch_bounds__(256) void k_stats(const float* __restrict__ f,
                                               const float* __restrict__ cent,
                                               const int* __restrict__ labels,
                                               float* ws) {
    int wid  = blockIdx.x * 4 + (threadIdx.x >> 6);   // 0..1023
    int lane = threadIdx.x & 63;
    float mu = 0.0f, sw = 0.0f;
    for (int i = wid; i < N_; i += 1024) {
        int l = labels[i];
        float x = f[i * D_ + lane];
        mu += x;
        float dv = x - cent[l * D_ + lane];
        sw += dv * dv;
        if (lane == 0) atomicAdd(&ws[WS_CNT + l], 1.0f);
    }
    #pragma unroll
    for (int m = 32; m >= 1; m >>= 1) sw += __shfl_xor(sw, m, 64);
    if (lane == 0) atomicAdd(&ws[WS_ACC + A_SW], sw);
    atomicAdd(&ws[WS_MU + lane], mu);
}

__global__ __launch_bounds__(256) void k_sb(const float* __restrict__ cent, float* ws) {
    int c = blockIdx.x * 256 + threadIdx.x;
    if (c >= NC_) return;
    float cnt = ws[WS_CNT + c];
    float s = 0.0f;
    const float invN = 1.0f / (float)N_;
    #pragma unroll
    for (int d = 0; d < D_; ++d) {
        float dv = cent[c * D_ + d] - ws[WS_MU + d] * invN;
        s += dv * dv;
    }
    atomicAdd(&ws[WS_ACC + A_SB], s * cnt);
}

__global__ __launch_bounds__(256) void k_gram(const float* __restrict__ cent, float* ws) {
    __shared__ float A[64 * 68];
    __shared__ float Bs[64 * 68];
    int bx = blockIdx.x & 15, by = blockIdx.x >> 4;
    int i0 = bx * 64, j0 = by * 64;
    int t = threadIdx.x;
    for (int q = t; q < 64 * 16; q += 256) {
        int r = q >> 4, dv = q & 15;
        float4 a = make_float4(0, 0, 0, 0), b = make_float4(0, 0, 0, 0);
        if (i0 + r < NC_) a = ((const float4*)(cent + (i0 + r) * D_))[dv];
        if (j0 + r < NC_) b = ((const float4*)(cent + (j0 + r) * D_))[dv];
        *(float4*)(A + r * 68 + dv * 4) = a;
        *(float4*)(Bs + r * 68 + dv * 4) = b;
    }
    __syncthreads();
    int ti = t >> 4, tj = t & 15;
    float lsum = 0.0f, lmin = 1e30f;
    #pragma unroll
    for (int a = 0; a < 4; ++a)
        #pragma unroll
        for (int b = 0; b < 4; ++b) {
            int il = ti + 16 * a, jl = tj + 16 * b;
            int gi = i0 + il, gj = j0 + jl;
            if (gi < NC_ && gj < NC_ && gi != gj) {
                float acc = 0.0f;
                #pragma unroll
                for (int k4 = 0; k4 < 16; ++k4) {
                    float4 a4 = *(const float4*)(A + il * 68 + k4 * 4);
                    float4 b4 = *(const float4*)(Bs + jl * 68 + k4 * 4);
                    acc += a4.x * b4.x + a4.y * b4.y + a4.z * b4.z + a4.w * b4.w;
                }
                float sq = fmaxf(2.0f - 2.0f * acc, 1e-12f);
                float d = sqrtf(sq);
                lsum += d;
                lmin = fminf(lmin, d);
            }
        }
    #pragma unroll
    for (int m = 32; m >= 1; m >>= 1) {
        lsum += __shfl_xor(lsum, m, 64);
        lmin = fminf(lmin, __shfl_xor(lmin, m, 64));
    }
    __shared__ float wsum[4], wmin[4];
    int wv = t >> 6;
    if ((t & 63) == 0) { wsum[wv] = lsum; wmin[wv] = lmin; }
    __syncthreads();
    if (t == 0) {
        float S = wsum[0] + wsum[1] + wsum[2] + wsum[3];
        float Mn = fminf(fminf(wmin[0], wmin[1]), fminf(wmin[2], wmin[3]));
        atomicAdd(&ws[WS_ACC + A_ISUM], S);
        atomicMin((unsigned int*)&ws[WS_ACC + A_IMIN], __float_as_uint(Mn));
    }
}

// CE + sup-block contrast partial: one wave per row, float4-vectorized
__global__ __launch_bounds__(256) void k_sup(const float* __restrict__ logits,
                                             const int* __restrict__ labels,
                                             const float* __restrict__ log_prior,
                                             const float* __restrict__ class_weight,
                                             float* ws) {
    __shared__ float lp[1024];
    int t = threadIdx.x;
    if (t < 250) ((float4*)lp)[t] = ((const float4*)log_prior)[t];
    __syncthreads();
    int w = t >> 6, l = t & 63;
    int row = blockIdx.x * 4 + w;
    const float* lrow = logits + (size_t)row * NC_;
    const float4* lrow4 = (const float4*)lrow;
    float4 v4[4];
    #pragma unroll
    for (int it = 0; it < 4; ++it) {
        int idx = it * 64 + l;
        v4[it] = (idx < 250) ? lrow4[idx]
                             : make_float4(-1e30f, -1e30f, -1e30f, -1e30f);
    }
    float vals[16];
    float m = -1e30f;
    #pragma unroll
    for (int it = 0; it < 4; ++it) {
        int idx = it * 64 + l;
        float4 p4 = (idx < 250) ? ((const float4*)lp)[idx]
                                : make_float4(0, 0, 0, 0);
        vals[it * 4 + 0] = v4[it].x + p4.x;
        vals[it * 4 + 1] = v4[it].y + p4.y;
        vals[it * 4 + 2] = v4[it].z + p4.z;
        vals[it * 4 + 3] = v4[it].w + p4.w;
        #pragma unroll
        for (int k = 0; k < 4; ++k) m = fmaxf(m, vals[it * 4 + k]);
    }
    #pragma unroll
    for (int msk = 1; msk < 64; msk <<= 1) m = fmaxf(m, __shfl_xor(m, msk, 64));
    float s1 = 0.0f, s20 = 0.0f;
    #pragma unroll
    for (int k = 0; k < 16; ++k) {
        float d = vals[k] - m;
        s1  += __expf(d);
        s20 += __expf(TEMP_INV * d);
    }
    #pragma unroll
    for (int msk = 1; msk < 64; msk <<= 1) {
        s1  += __shfl_xor(s1, msk, 64);
        s20 += __shfl_xor(s20, msk, 64);
    }
    if (l == 0) {
        int lab = labels[row];
        float vpos = lrow[lab] + lp[lab];
        float wt = class_weight[lab];
        atomicAdd(&ws[WS_ACC + A_CENUM], wt * (m + __logf(s1) - vpos));
        atomicAdd(&ws[WS_ACC + A_CEDEN], wt);
        ws[WS_SUPM + row] = TEMP_INV * m;
        ws[WS_PS + (size_t)row * PCH + (PCH - 1)] = s20;
        ws[WS_PSUP + row] = TEMP_INV * vpos;
    }
}

// MFMA GEMM f @ B^T fused with per-chunk sumexp (fixed reference M0).
// grid (64, 72); block 256 = 4 waves in 2x2; wave tile 32 rows x 64 cols.
__global__ __launch_bounds__(256) void k_gemm(const ushort* __restrict__ B,
                                              const int* __restrict__ labels,
                                              float* __restrict__ ws) {
    int l = threadIdx.x & 63;
    int w = threadIdx.x >> 6;
    int wm = w >> 1, wn = w & 1;
    int r0 = blockIdx.x * 64 + wm * 32;
    int c0 = blockIdx.y * 128 + wn * 64;
    int lr = l & 15, g = l >> 4;
    int lk = g * 8;

    const ushort* Af = B + (size_t)(NC_ + r0 + lr) * D_ + lk;
    const ushort* Bf = B + (size_t)(c0 + lr) * D_ + lk;

    short8_t a[2][2], b[4][2];
    #pragma unroll
    for (int rf = 0; rf < 2; ++rf)
        #pragma unroll
        for (int ks = 0; ks < 2; ++ks)
            a[rf][ks] = *(const short8_t*)(Af + rf * 16 * D_ + ks * 32);
    #pragma unroll
    for (int cf = 0; cf < 4; ++cf)
        #pragma unroll
        for (int ks = 0; ks < 2; ++ks)
            b[cf][ks] = *(const short8_t*)(Bf + cf * 16 * D_ + ks * 32);

    f32x4 acc[2][4] = {};
    #pragma unroll
    for (int ks = 0; ks < 2; ++ks)
        #pragma unroll
        for (int rf = 0; rf < 2; ++rf)
            #pragma unroll
            for (int cf = 0; cf < 4; ++cf)
                acc[rf][cf] = __builtin_amdgcn_mfma_f32_16x16x32_bf16(
                    a[rf][ks], b[cf][ks], acc[rf][cf], 0, 0, 0);

    // positive-center extraction (only col blocks covering cols < 1000)
    if (c0 < NC_) {
        #pragma unroll
        for (int rf = 0; rf < 2; ++rf)
            #pragma unroll
            for (int reg = 0; reg < 4; ++reg) {
                int row = r0 + rf * 16 + g * 4 + reg;
                int lab = labels[row];
                #pragma unroll
                for (int cf = 0; cf < 4; ++cf) {
                    int col = c0 + cf * 16 + lr;
                    if (col == lab) ws[WS_PCENT + row] = acc[rf][cf][reg];
                }
            }
    }

    // per-row sumexp with fixed reference M0 (no max pass needed: dots <= 1)
    __shared__ float ssum[64][2];
    #pragma unroll
    for (int rf = 0; rf < 2; ++rf) {
        float se[4] = {0, 0, 0, 0};
        #pragma unroll
        for (int cf = 0; cf < 4; ++cf) {
            int col = c0 + cf * 16 + lr;
            bool valid = col < VCOLS;
            #pragma unroll
            for (int reg = 0; reg < 4; ++reg) {
                float v = valid ? acc[rf][cf][reg] * TEMP_INV - M0 : -1e30f;
                se[reg] += __expf(v);
            }
        }
        #pragma unroll
        for (int reg = 0; reg < 4; ++reg) {
            #pragma unroll
            for (int msk = 1; msk < 16; msk <<= 1)
                se[reg] += __shfl_xor(se[reg], msk, 64);
            if (lr == 0) ssum[wm * 32 + rf * 16 + g * 4 + reg][wn] = se[reg];
        }
    }
    __syncthreads();
    int t = threadIdx.x;
    if (t < 64) {
        int row = blockIdx.x * 64 + t;
        ws[WS_PS + (size_t)row * PCH + blockIdx.y] = ssum[t][0] + ssum[t][1];
    }
}

// per-row merge: sum 72 gemm chunk sums (ref M0) + sup chunk (its own max)
__global__ __launch_bounds__(256) void k_red(float* ws) {
    int w = threadIdx.x >> 6, l = threadIdx.x & 63;
    int row = blockIdx.x * 4 + w;
    const float* pv = ws + WS_PS + (size_t)row * PCH;
    float s = pv[l];                       // chunks 0..63
    if (l < 8) s += pv[l + 64];            // chunks 64..71
    #pragma unroll
    for (int msk = 1; msk < 64; msk <<= 1) s += __shfl_xor(s, msk, 64);
    if (l == 0) {
        float msup = ws[WS_SUPM + row];
        float ssup = pv[PCH - 1];
        float M = fmaxf(M0, msup);
        float stot = s * __expf(M0 - M) + ssup * __expf(msup - M);
        float logS = __logf(stot + 1e-12f);
        float lp1 = ws[WS_PSUP + row] - M - logS;
        float lp2 = ws[WS_PCENT + row] * TEMP_INV - M - logS;
        atomicAdd(&ws[WS_ACC + A_CSUM], (lp1 + 0.02f * lp2) / (1.02f + 1e-12f));
    }
}

__global__ void k_final(const float* __restrict__ ws, float* __restrict__ out) {
    float ce = ws[WS_ACC + A_CENUM] / ws[WS_ACC + A_CEDEN];
    float contrast = -(ws[WS_ACC + A_CSUM] / (float)N_);
    float inter_mean = ws[WS_ACC + A_ISUM] / (float)(NC_ * (NC_ - 1));
    float inter_min = __uint_as_float(((const unsigned*)ws)[WS_ACC + A_IMIN]);
    float sw = ws[WS_ACC + A_SW];
    float sb = ws[WS_ACC + A_SB];
    float intra = sw / (float)N_;
    float fisher = sb / (sw + 1e-6f);
    float reg = 1.0f * intra + 0.1f / (inter_mean + 1e-6f)
              + 0.05f / (inter_min + 1e-6f) + 0.1f / (fisher + 1e-6f);
    out[0] = ce + contrast + reg;
}

extern "C" void kernel_launch(void* const* d_in, const int* in_sizes, int n_in,
                              void* d_out, int out_size, void* d_ws, size_t ws_size,
                              hipStream_t stream) {
    const float* feats        = (const float*)d_in[0];
    const float* logits       = (const float*)d_in[1];
    const int*   labels       = (const int*)d_in[2];
    const float* C            = (const float*)d_in[3];
    const float* queue        = (const float*)d_in[4];
    const float* log_prior    = (const float*)d_in[5];
    const float* class_weight = (const float*)d_in[6];
    float* ws  = (float*)d_ws;
    float* out = (float*)d_out;
    ushort* Bbf = (ushort*)(ws + WS_BBF);

    hipLaunchKernelGGL(k_init,  dim3(4),    dim3(256), 0, stream, ws);
    hipLaunchKernelGGL(k_prep,  dim3(2058), dim3(256), 0, stream,
                       feats, C, queue, ws + WS_F, ws + WS_CENT, Bbf);
    hipLaunchKernelGGL(k_stats, dim3(256),  dim3(256), 0, stream,
                       ws + WS_F, ws + WS_CENT, labels, ws);
    hipLaunchKernelGGL(k_sb,    dim3(4),    dim3(256), 0, stream, ws + WS_CENT, ws);
    hipLaunchKernelGGL(k_gram,  dim3(256),  dim3(256), 0, stream, ws + WS_CENT, ws);
    hipLaunchKernelGGL(k_sup,   dim3(N_/4), dim3(256), 0, stream,
                       logits, labels, log_prior, class_weight, ws);
    hipLaunchKernelGGL(k_gemm,  dim3(64, 72), dim3(256), 0, stream, Bbf, labels, ws);
    hipLaunchKernelGGL(k_red,   dim3(N_/4), dim3(256), 0, stream, ws);
    hipLaunchKernelGGL(k_final, dim3(1),    dim3(1),   0, stream, ws, out);
}

// Round 4
// 81.367 us; speedup vs baseline: 3.1686x; 3.1686x over previous
//
#include <hip/hip_runtime.h>
#include <math.h>

#define N_ 4096
#define D_ 64
#define NC_ 1000
#define KQ_ 8192
#define VCOLS 9192          // NC + KQ real columns
#define VPAD  9216          // 72*128 padded
#define PCH   73            // 72 gemm chunks + 1 sup chunk
#define TEMP_INV 20.0f
#define M0 20.25f           // fixed softmax reference for gemm chunks (dots <= 1)

// workspace layout (float offsets)
#define WS_F     0
#define WS_CENT  (WS_F + N_*D_)
#define WS_MU    (WS_CENT + NC_*D_)
#define WS_CNT   (WS_MU + D_)
#define WS_SUPM  (WS_CNT + NC_)
#define WS_PSUP  (WS_SUPM + N_)
#define WS_PCENT (WS_PSUP + N_)
#define WS_CEPN  (WS_PCENT + N_)     // 1024 per-block CE numerator partials
#define WS_CEPD  (WS_CEPN + 1024)    // 1024 CE denominator partials
#define WS_CSP   (WS_CEPD + 1024)    // 1024 contrast partials
#define WS_GSUM  (WS_CSP + 1024)     // 256 gram dist-sum partials
#define WS_GMIN  (WS_GSUM + 256)     // 256 gram dist-min partials
#define WS_SWP   (WS_GMIN + 256)     // 64 S_W partials
#define WS_SBP   (WS_SWP + 64)       // 16 S_B partials
#define WS_PS    (WS_SBP + 16)       // N*PCH chunk sums
#define WS_BBF   (WS_PS + N_*PCH)    // ushort[VPAD*64]

typedef __attribute__((ext_vector_type(8))) short short8_t;
typedef __attribute__((ext_vector_type(4))) float f32x4;

__device__ __forceinline__ ushort f2bf(float x) {
    union { float f; unsigned u; } v; v.f = x;
    unsigned r = (v.u + 0x7FFFu + ((v.u >> 16) & 1u)) >> 16;
    return (ushort)r;
}

__global__ __launch_bounds__(256) void k_init(float* ws) {
    int t = blockIdx.x * 256 + threadIdx.x;
    if (t < NC_) ws[WS_CNT + t] = 0.0f;
    if (t < D_)  ws[WS_MU + t] = 0.0f;
}

// merged prep: norm_f rows (blocks 0..1023), norm_c cols (1024..1027),
// queue-tail bf16 (1028..2057)
__global__ __launch_bounds__(256) void k_prep(const float* __restrict__ feats,
                                              const float* __restrict__ C,
                                              const float* __restrict__ queue,
                                              float* __restrict__ f,
                                              float* __restrict__ cent,
                                              ushort* __restrict__ B) {
    int b = blockIdx.x;
    if (b < 1024) {
        int row  = b * 4 + (threadIdx.x >> 6);
        int lane = threadIdx.x & 63;
        float x = feats[row * D_ + lane];
        float ss = x * x;
        #pragma unroll
        for (int m = 32; m >= 1; m >>= 1) ss += __shfl_xor(ss, m, 64);
        float y = x / fmaxf(sqrtf(ss), 1e-12f);
        f[row * D_ + lane] = y;
        B[(size_t)(NC_ + row) * D_ + lane] = f2bf(y);
    } else if (b < 1028) {
        int c = (b - 1024) * 256 + threadIdx.x;
        if (c >= NC_) return;
        float v[D_];
        float ss = 0.0f;
        #pragma unroll
        for (int d = 0; d < D_; ++d) { float x = C[d * NC_ + c]; v[d] = x; ss += x * x; }
        float inv = 1.0f / fmaxf(sqrtf(ss), 1e-12f);
        #pragma unroll
        for (int d = 0; d < D_; ++d) {
            float y = v[d] * inv;
            cent[c * D_ + d] = y;
            B[(size_t)c * D_ + d] = f2bf(y);
        }
    } else {
        int t = (b - 1028) * 256 + threadIdx.x;   // over (4096+24)*64
        if (t >= (KQ_ - N_ + 24) * D_) return;
        int r = t >> 6, d = t & 63;
        ushort o = 0;
        if (r < KQ_ - N_) o = f2bf(queue[(size_t)(N_ + r) * D_ + d]);
        B[(size_t)(NC_ + N_ + r) * D_ + d] = o;
    }
}

// mu (64-addr atomics), cls_cnt (spread atomics), S_W partials: 64 blocks
__global__ __launch_bounds__(256) void k_stats(const float* __restrict__ f,
                                               const float* __restrict__ cent,
                                               const int* __restrict__ labels,
                                               float* ws) {
    __shared__ float lmu[4][64];
    __shared__ float lsw[4];
    int w = threadIdx.x >> 6, lane = threadIdx.x & 63;
    int wid = blockIdx.x * 4 + w;   // 0..255
    float mu = 0.0f, sw = 0.0f;
    for (int i = wid; i < N_; i += 256) {
        int l = labels[i];
        float x = f[i * D_ + lane];
        mu += x;
        float dv = x - cent[l * D_ + lane];
        sw += dv * dv;
        if (lane == 0) atomicAdd(&ws[WS_CNT + l], 1.0f);
    }
    #pragma unroll
    for (int m = 32; m >= 1; m >>= 1) sw += __shfl_xor(sw, m, 64);
    lmu[w][lane] = mu;
    if (lane == 0) lsw[w] = sw;
    __syncthreads();
    if (w == 0) {
        float s = lmu[0][lane] + lmu[1][lane] + lmu[2][lane] + lmu[3][lane];
        atomicAdd(&ws[WS_MU + lane], s);
        if (lane == 0)
            ws[WS_SWP + blockIdx.x] = lsw[0] + lsw[1] + lsw[2] + lsw[3];
    }
}

// S_B partials: 4 blocks x 256; per-wave shuffle reduce -> WS_SBP[16]
__global__ __launch_bounds__(256) void k_sb(const float* __restrict__ cent, float* ws) {
    int c = blockIdx.x * 256 + threadIdx.x;
    int w = threadIdx.x >> 6, lane = threadIdx.x & 63;
    float s = 0.0f;
    if (c < NC_) {
        float cnt = ws[WS_CNT + c];
        const float invN = 1.0f / (float)N_;
        float acc = 0.0f;
        #pragma unroll
        for (int d = 0; d < D_; ++d) {
            float dv = cent[c * D_ + d] - ws[WS_MU + d] * invN;
            acc += dv * dv;
        }
        s = acc * cnt;
    }
    #pragma unroll
    for (int m = 32; m >= 1; m >>= 1) s += __shfl_xor(s, m, 64);
    if (lane == 0) ws[WS_SBP + blockIdx.x * 4 + w] = s;
}

// gram -> per-block (sum, min) partials
__global__ __launch_bounds__(256) void k_gram(const float* __restrict__ cent, float* ws) {
    __shared__ float A[64 * 68];
    __shared__ float Bs[64 * 68];
    int bx = blockIdx.x & 15, by = blockIdx.x >> 4;
    int i0 = bx * 64, j0 = by * 64;
    int t = threadIdx.x;
    for (int q = t; q < 64 * 16; q += 256) {
        int r = q >> 4, dv = q & 15;
        float4 a = make_float4(0, 0, 0, 0), b = make_float4(0, 0, 0, 0);
        if (i0 + r < NC_) a = ((const float4*)(cent + (i0 + r) * D_))[dv];
        if (j0 + r < NC_) b = ((const float4*)(cent + (j0 + r) * D_))[dv];
        *(float4*)(A + r * 68 + dv * 4) = a;
        *(float4*)(Bs + r * 68 + dv * 4) = b;
    }
    __syncthreads();
    int ti = t >> 4, tj = t & 15;
    float lsum = 0.0f, lmin = 1e30f;
    #pragma unroll
    for (int a = 0; a < 4; ++a)
        #pragma unroll
        for (int b = 0; b < 4; ++b) {
            int il = ti + 16 * a, jl = tj + 16 * b;
            int gi = i0 + il, gj = j0 + jl;
            if (gi < NC_ && gj < NC_ && gi != gj) {
                float acc = 0.0f;
                #pragma unroll
                for (int k4 = 0; k4 < 16; ++k4) {
                    float4 a4 = *(const float4*)(A + il * 68 + k4 * 4);
                    float4 b4 = *(const float4*)(Bs + jl * 68 + k4 * 4);
                    acc += a4.x * b4.x + a4.y * b4.y + a4.z * b4.z + a4.w * b4.w;
                }
                float sq = fmaxf(2.0f - 2.0f * acc, 1e-12f);
                float d = sqrtf(sq);
                lsum += d;
                lmin = fminf(lmin, d);
            }
        }
    #pragma unroll
    for (int m = 32; m >= 1; m >>= 1) {
        lsum += __shfl_xor(lsum, m, 64);
        lmin = fminf(lmin, __shfl_xor(lmin, m, 64));
    }
    __shared__ float wsum[4], wmin[4];
    int wv = t >> 6;
    if ((t & 63) == 0) { wsum[wv] = lsum; wmin[wv] = lmin; }
    __syncthreads();
    if (t == 0) {
        ws[WS_GSUM + blockIdx.x] = wsum[0] + wsum[1] + wsum[2] + wsum[3];
        ws[WS_GMIN + blockIdx.x] = fminf(fminf(wmin[0], wmin[1]),
                                         fminf(wmin[2], wmin[3]));
    }
}

// CE + sup-block contrast partial: one wave per row; per-block CE partials
__global__ __launch_bounds__(256) void k_sup(const float* __restrict__ logits,
                                             const int* __restrict__ labels,
                                             const float* __restrict__ log_prior,
                                             const float* __restrict__ class_weight,
                                             float* ws) {
    __shared__ float lp[1024];
    __shared__ float cep[4][2];
    int t = threadIdx.x;
    if (t < 250) ((float4*)lp)[t] = ((const float4*)log_prior)[t];
    __syncthreads();
    int w = t >> 6, l = t & 63;
    int row = blockIdx.x * 4 + w;
    const float* lrow = logits + (size_t)row * NC_;
    const float4* lrow4 = (const float4*)lrow;
    float4 v4[4];
    #pragma unroll
    for (int it = 0; it < 4; ++it) {
        int idx = it * 64 + l;
        v4[it] = (idx < 250) ? lrow4[idx]
                             : make_float4(-1e30f, -1e30f, -1e30f, -1e30f);
    }
    float vals[16];
    float m = -1e30f;
    #pragma unroll
    for (int it = 0; it < 4; ++it) {
        int idx = it * 64 + l;
        float4 p4 = (idx < 250) ? ((const float4*)lp)[idx]
                                : make_float4(0, 0, 0, 0);
        vals[it * 4 + 0] = v4[it].x + p4.x;
        vals[it * 4 + 1] = v4[it].y + p4.y;
        vals[it * 4 + 2] = v4[it].z + p4.z;
        vals[it * 4 + 3] = v4[it].w + p4.w;
        #pragma unroll
        for (int k = 0; k < 4; ++k) m = fmaxf(m, vals[it * 4 + k]);
    }
    #pragma unroll
    for (int msk = 1; msk < 64; msk <<= 1) m = fmaxf(m, __shfl_xor(m, msk, 64));
    float s1 = 0.0f, s20 = 0.0f;
    #pragma unroll
    for (int k = 0; k < 16; ++k) {
        float d = vals[k] - m;
        s1  += __expf(d);
        s20 += __expf(TEMP_INV * d);
    }
    #pragma unroll
    for (int msk = 1; msk < 64; msk <<= 1) {
        s1  += __shfl_xor(s1, msk, 64);
        s20 += __shfl_xor(s20, msk, 64);
    }
    if (l == 0) {
        int lab = labels[row];
        float vpos = lrow[lab] + lp[lab];
        float wt = class_weight[lab];
        cep[w][0] = wt * (m + __logf(s1) - vpos);
        cep[w][1] = wt;
        ws[WS_SUPM + row] = TEMP_INV * m;
        ws[WS_PS + (size_t)row * PCH + (PCH - 1)] = s20;
        ws[WS_PSUP + row] = TEMP_INV * vpos;
    }
    __syncthreads();
    if (t == 0) {
        ws[WS_CEPN + blockIdx.x] = cep[0][0] + cep[1][0] + cep[2][0] + cep[3][0];
        ws[WS_CEPD + blockIdx.x] = cep[0][1] + cep[1][1] + cep[2][1] + cep[3][1];
    }
}

// MFMA GEMM f @ B^T fused with per-chunk sumexp (fixed reference M0).
// grid (64, 72); block 256 = 4 waves in 2x2; wave tile 32 rows x 64 cols.
__global__ __launch_bounds__(256) void k_gemm(const ushort* __restrict__ B,
                                              const int* __restrict__ labels,
                                              float* __restrict__ ws) {
    int l = threadIdx.x & 63;
    int w = threadIdx.x >> 6;
    int wm = w >> 1, wn = w & 1;
    int r0 = blockIdx.x * 64 + wm * 32;
    int c0 = blockIdx.y * 128 + wn * 64;
    int lr = l & 15, g = l >> 4;
    int lk = g * 8;

    const ushort* Af = B + (size_t)(NC_ + r0 + lr) * D_ + lk;
    const ushort* Bf = B + (size_t)(c0 + lr) * D_ + lk;

    short8_t a[2][2], b[4][2];
    #pragma unroll
    for (int rf = 0; rf < 2; ++rf)
        #pragma unroll
        for (int ks = 0; ks < 2; ++ks)
            a[rf][ks] = *(const short8_t*)(Af + rf * 16 * D_ + ks * 32);
    #pragma unroll
    for (int cf = 0; cf < 4; ++cf)
        #pragma unroll
        for (int ks = 0; ks < 2; ++ks)
            b[cf][ks] = *(const short8_t*)(Bf + cf * 16 * D_ + ks * 32);

    f32x4 acc[2][4] = {};
    #pragma unroll
    for (int ks = 0; ks < 2; ++ks)
        #pragma unroll
        for (int rf = 0; rf < 2; ++rf)
            #pragma unroll
            for (int cf = 0; cf < 4; ++cf)
                acc[rf][cf] = __builtin_amdgcn_mfma_f32_16x16x32_bf16(
                    a[rf][ks], b[cf][ks], acc[rf][cf], 0, 0, 0);

    // positive-center extraction (only col blocks covering cols < 1000)
    if (c0 < NC_) {
        #pragma unroll
        for (int rf = 0; rf < 2; ++rf)
            #pragma unroll
            for (int reg = 0; reg < 4; ++reg) {
                int row = r0 + rf * 16 + g * 4 + reg;
                int lab = labels[row];
                #pragma unroll
                for (int cf = 0; cf < 4; ++cf) {
                    int col = c0 + cf * 16 + lr;
                    if (col == lab) ws[WS_PCENT + row] = acc[rf][cf][reg];
                }
            }
    }

    // per-row sumexp with fixed reference M0 (no max pass needed: dots <= 1)
    __shared__ float ssum[64][2];
    #pragma unroll
    for (int rf = 0; rf < 2; ++rf) {
        float se[4] = {0, 0, 0, 0};
        #pragma unroll
        for (int cf = 0; cf < 4; ++cf) {
            int col = c0 + cf * 16 + lr;
            bool valid = col < VCOLS;
            #pragma unroll
            for (int reg = 0; reg < 4; ++reg) {
                float v = valid ? acc[rf][cf][reg] * TEMP_INV - M0 : -1e30f;
                se[reg] += __expf(v);
            }
        }
        #pragma unroll
        for (int reg = 0; reg < 4; ++reg) {
            #pragma unroll
            for (int msk = 1; msk < 16; msk <<= 1)
                se[reg] += __shfl_xor(se[reg], msk, 64);
            if (lr == 0) ssum[wm * 32 + rf * 16 + g * 4 + reg][wn] = se[reg];
        }
    }
    __syncthreads();
    int t = threadIdx.x;
    if (t < 64) {
        int row = blockIdx.x * 64 + t;
        ws[WS_PS + (size_t)row * PCH + blockIdx.y] = ssum[t][0] + ssum[t][1];
    }
}

// per-row merge -> per-block contrast partials (no same-address atomics)
__global__ __launch_bounds__(256) void k_red(float* ws) {
    __shared__ float cb[4];
    int w = threadIdx.x >> 6, l = threadIdx.x & 63;
    int row = blockIdx.x * 4 + w;
    const float* pv = ws + WS_PS + (size_t)row * PCH;
    float s = pv[l];                       // chunks 0..63
    if (l < 8) s += pv[l + 64];            // chunks 64..71
    #pragma unroll
    for (int msk = 1; msk < 64; msk <<= 1) s += __shfl_xor(s, msk, 64);
    if (l == 0) {
        float msup = ws[WS_SUPM + row];
        float ssup = pv[PCH - 1];
        float M = fmaxf(M0, msup);
        float stot = s * __expf(M0 - M) + ssup * __expf(msup - M);
        float logS = __logf(stot + 1e-12f);
        float lp1 = ws[WS_PSUP + row] - M - logS;
        float lp2 = ws[WS_PCENT + row] * TEMP_INV - M - logS;
        cb[w] = (lp1 + 0.02f * lp2) / (1.02f + 1e-12f);
    }
    __syncthreads();
    if (threadIdx.x == 0)
        ws[WS_CSP + blockIdx.x] = cb[0] + cb[1] + cb[2] + cb[3];
}

// single-block tree reduce of all partial arrays + final scalar
__global__ __launch_bounds__(256) void k_final(const float* __restrict__ ws,
                                               float* __restrict__ out) {
    int t = threadIdx.x;
    float cen = 0, ced = 0, csum = 0, swp = 0, sbp = 0;
    #pragma unroll
    for (int k = 0; k < 4; ++k) {
        int idx = t + k * 256;
        cen  += ws[WS_CEPN + idx];
        ced  += ws[WS_CEPD + idx];
        csum += ws[WS_CSP + idx];
    }
    float gsum = ws[WS_GSUM + t];
    float gmin = ws[WS_GMIN + t];
    if (t < 64) swp = ws[WS_SWP + t];
    if (t < 16) sbp = ws[WS_SBP + t];
    #pragma unroll
    for (int m = 32; m >= 1; m >>= 1) {
        cen  += __shfl_xor(cen, m, 64);
        ced  += __shfl_xor(ced, m, 64);
        csum += __shfl_xor(csum, m, 64);
        gsum += __shfl_xor(gsum, m, 64);
        swp  += __shfl_xor(swp, m, 64);
        sbp  += __shfl_xor(sbp, m, 64);
        gmin = fminf(gmin, __shfl_xor(gmin, m, 64));
    }
    __shared__ float red[4][7];
    int w = t >> 6;
    if ((t & 63) == 0) {
        red[w][0] = cen; red[w][1] = ced; red[w][2] = csum;
        red[w][3] = gsum; red[w][4] = swp; red[w][5] = sbp; red[w][6] = gmin;
    }
    __syncthreads();
    if (t == 0) {
        float CEN = red[0][0] + red[1][0] + red[2][0] + red[3][0];
        float CED = red[0][1] + red[1][1] + red[2][1] + red[3][1];
        float CSM = red[0][2] + red[1][2] + red[2][2] + red[3][2];
        float GSM = red[0][3] + red[1][3] + red[2][3] + red[3][3];
        float SW  = red[0][4] + red[1][4] + red[2][4] + red[3][4];
        float SB  = red[0][5] + red[1][5] + red[2][5] + red[3][5];
        float GMN = fminf(fminf(red[0][6], red[1][6]), fminf(red[2][6], red[3][6]));
        float ce = CEN / CED;
        float contrast = -(CSM / (float)N_);
        float inter_mean = GSM / (float)(NC_ * (NC_ - 1));
        float intra = SW / (float)N_;
        float fisher = SB / (SW + 1e-6f);
        float reg = 1.0f * intra + 0.1f / (inter_mean + 1e-6f)
                  + 0.05f / (GMN + 1e-6f) + 0.1f / (fisher + 1e-6f);
        out[0] = ce + contrast + reg;
    }
}

extern "C" void kernel_launch(void* const* d_in, const int* in_sizes, int n_in,
                              void* d_out, int out_size, void* d_ws, size_t ws_size,
                              hipStream_t stream) {
    const float* feats        = (const float*)d_in[0];
    const float* logits       = (const float*)d_in[1];
    const int*   labels       = (const int*)d_in[2];
    const float* C            = (const float*)d_in[3];
    const float* queue        = (const float*)d_in[4];
    const float* log_prior    = (const float*)d_in[5];
    const float* class_weight = (const float*)d_in[6];
    float* ws  = (float*)d_ws;
    float* out = (float*)d_out;
    ushort* Bbf = (ushort*)(ws + WS_BBF);

    hipLaunchKernelGGL(k_init,  dim3(4),    dim3(256), 0, stream, ws);
    hipLaunchKernelGGL(k_prep,  dim3(2058), dim3(256), 0, stream,
                       feats, C, queue, ws + WS_F, ws + WS_CENT, Bbf);
    hipLaunchKernelGGL(k_stats, dim3(64),   dim3(256), 0, stream,
                       ws + WS_F, ws + WS_CENT, labels, ws);
    hipLaunchKernelGGL(k_sb,    dim3(4),    dim3(256), 0, stream, ws + WS_CENT, ws);
    hipLaunchKernelGGL(k_gram,  dim3(256),  dim3(256), 0, stream, ws + WS_CENT, ws);
    hipLaunchKernelGGL(k_sup,   dim3(N_/4), dim3(256), 0, stream,
                       logits, labels, log_prior, class_weight, ws);
    hipLaunchKernelGGL(k_gemm,  dim3(64, 72), dim3(256), 0, stream, Bbf, labels, ws);
    hipLaunchKernelGGL(k_red,   dim3(N_/4), dim3(256), 0, stream, ws);
    hipLaunchKernelGGL(k_final, dim3(1),    dim3(256), 0, stream, ws, out);
}

// Round 5
// 55.151 us; speedup vs baseline: 4.6748x; 1.4753x over previous
//
#include <hip/hip_runtime.h>
#include <math.h>

#define N_ 4096
#define D_ 64
#define NC_ 1000
#define KQ_ 8192
#define VCOLS 9192          // NC + KQ real columns
#define VPAD  9216          // 72*128 padded
#define PCH   73            // 72 gemm chunks + 1 sup chunk
#define TEMP_INV 20.0f
#define M0 20.25f           // fixed softmax reference for gemm chunks (dots <= 1)

// workspace layout (float offsets)
#define WS_F     0
#define WS_CENT  (WS_F + N_*D_)
#define WS_SUPM  (WS_CENT + NC_*D_)
#define WS_PSUP  (WS_SUPM + N_)
#define WS_PCENT (WS_PSUP + N_)
#define WS_CEPN  (WS_PCENT + N_)     // 64 CE numerator partials
#define WS_CEPD  (WS_CEPN + 64)      // 64 CE denominator partials
#define WS_CSP   (WS_CEPD + 64)      // 1024 contrast partials
#define WS_GS    (WS_CSP + 1024)     // 128 gram dist-sum partials
#define WS_GM    (WS_GS + 128)       // 128 gram dist-min partials
#define WS_VF    (WS_GM + 128)       // 64 blocks x 64 dims: sum f
#define WS_VC    (WS_VF + 4096)      // 64 blocks x 64 dims: sum cent[label]
#define WS_TP    (WS_VC + 4096)      // 64: sum f.cent[label] partials
#define WS_PS    (WS_TP + 64)        // N*PCH chunk sums
#define WS_BBF   (WS_PS + N_*PCH)    // ushort[VPAD*64]

typedef __attribute__((ext_vector_type(8))) short short8_t;
typedef __attribute__((ext_vector_type(4))) float f32x4;

__device__ __forceinline__ ushort f2bf(float x) {
    union { float f; unsigned u; } v; v.f = x;
    unsigned r = (v.u + 0x7FFFu + ((v.u >> 16) & 1u)) >> 16;
    return (ushort)r;
}

// merged prep: norm_f rows (blocks 0..1023), norm_c cols (1024..1027),
// queue-tail bf16 (1028..2057)
__global__ __launch_bounds__(256) void k_prep(const float* __restrict__ feats,
                                              const float* __restrict__ C,
                                              const float* __restrict__ queue,
                                              float* __restrict__ f,
                                              float* __restrict__ cent,
                                              ushort* __restrict__ B) {
    int b = blockIdx.x;
    if (b < 1024) {
        int row  = b * 4 + (threadIdx.x >> 6);
        int lane = threadIdx.x & 63;
        float x = feats[row * D_ + lane];
        float ss = x * x;
        #pragma unroll
        for (int m = 32; m >= 1; m >>= 1) ss += __shfl_xor(ss, m, 64);
        float y = x / fmaxf(sqrtf(ss), 1e-12f);
        f[row * D_ + lane] = y;
        B[(size_t)(NC_ + row) * D_ + lane] = f2bf(y);
    } else if (b < 1028) {
        int c = (b - 1024) * 256 + threadIdx.x;
        if (c >= NC_) return;
        float v[D_];
        float ss = 0.0f;
        #pragma unroll
        for (int d = 0; d < D_; ++d) { float x = C[d * NC_ + c]; v[d] = x; ss += x * x; }
        float inv = 1.0f / fmaxf(sqrtf(ss), 1e-12f);
        #pragma unroll
        for (int d = 0; d < D_; ++d) {
            float y = v[d] * inv;
            cent[c * D_ + d] = y;
            B[(size_t)c * D_ + d] = f2bf(y);
        }
    } else {
        int t = (b - 1028) * 256 + threadIdx.x;   // over (4096+24)*64
        if (t >= (KQ_ - N_ + 24) * D_) return;
        int r = t >> 6, d = t & 63;
        ushort o = 0;
        if (r < KQ_ - N_) o = f2bf(queue[(size_t)(N_ + r) * D_ + d]);
        B[(size_t)(NC_ + N_ + r) * D_ + d] = o;
    }
}

// mega kernel, grid (64, 76):
//   by==0      : sup CE + sup-chunk contrast partials (64 rows per bx)
//   by==1..2   : gram via MFMA (128 blocks)
//   by==3      : stats partials (sum f, sum cent[l], sum f.cent[l])
//   by>=4      : gemm chunk cy=by-4 (72 chunks of 128 cols)
__global__ __launch_bounds__(256) void k_mega(const ushort* __restrict__ B,
                                              const float* __restrict__ logits,
                                              const int* __restrict__ labels,
                                              const float* __restrict__ log_prior,
                                              const float* __restrict__ class_weight,
                                              const float* __restrict__ f,
                                              const float* __restrict__ cent,
                                              float* __restrict__ ws) {
    int t = threadIdx.x;
    int l = t & 63, w = t >> 6;
    int bx = blockIdx.x, by = blockIdx.y;

    if (by >= 4) {
        // ---------------- GEMM chunk ----------------
        int cy = by - 4;
        int wm = w >> 1, wn = w & 1;
        int r0 = bx * 64 + wm * 32;
        int c0 = cy * 128 + wn * 64;
        int lr = l & 15, lg = l >> 4;
        int lk = lg * 8;

        const ushort* Af = B + (size_t)(NC_ + r0 + lr) * D_ + lk;
        const ushort* Bf = B + (size_t)(c0 + lr) * D_ + lk;

        short8_t a[2][2], b[4][2];
        #pragma unroll
        for (int rf = 0; rf < 2; ++rf)
            #pragma unroll
            for (int ks = 0; ks < 2; ++ks)
                a[rf][ks] = *(const short8_t*)(Af + rf * 16 * D_ + ks * 32);
        #pragma unroll
        for (int cf = 0; cf < 4; ++cf)
            #pragma unroll
            for (int ks = 0; ks < 2; ++ks)
                b[cf][ks] = *(const short8_t*)(Bf + cf * 16 * D_ + ks * 32);

        f32x4 acc[2][4] = {};
        #pragma unroll
        for (int ks = 0; ks < 2; ++ks)
            #pragma unroll
            for (int rf = 0; rf < 2; ++rf)
                #pragma unroll
                for (int cf = 0; cf < 4; ++cf)
                    acc[rf][cf] = __builtin_amdgcn_mfma_f32_16x16x32_bf16(
                        a[rf][ks], b[cf][ks], acc[rf][cf], 0, 0, 0);

        // positive-center extraction (only col blocks covering cols < 1000)
        if (c0 < NC_) {
            #pragma unroll
            for (int rf = 0; rf < 2; ++rf)
                #pragma unroll
                for (int reg = 0; reg < 4; ++reg) {
                    int row = r0 + rf * 16 + lg * 4 + reg;
                    int lab = labels[row];
                    #pragma unroll
                    for (int cf = 0; cf < 4; ++cf) {
                        int col = c0 + cf * 16 + lr;
                        if (col == lab) ws[WS_PCENT + row] = acc[rf][cf][reg];
                    }
                }
        }

        // per-row sumexp with fixed reference M0 (dots <= 1)
        __shared__ float ssum[64][2];
        #pragma unroll
        for (int rf = 0; rf < 2; ++rf) {
            float se[4] = {0, 0, 0, 0};
            #pragma unroll
            for (int cf = 0; cf < 4; ++cf) {
                int col = c0 + cf * 16 + lr;
                bool valid = col < VCOLS;
                #pragma unroll
                for (int reg = 0; reg < 4; ++reg) {
                    float v = valid ? acc[rf][cf][reg] * TEMP_INV - M0 : -1e30f;
                    se[reg] += __expf(v);
                }
            }
            #pragma unroll
            for (int reg = 0; reg < 4; ++reg) {
                #pragma unroll
                for (int msk = 1; msk < 16; msk <<= 1)
                    se[reg] += __shfl_xor(se[reg], msk, 64);
                if (lr == 0) ssum[wm * 32 + rf * 16 + lg * 4 + reg][wn] = se[reg];
            }
        }
        __syncthreads();
        if (t < 64) {
            int row = bx * 64 + t;
            ws[WS_PS + (size_t)row * PCH + cy] = ssum[t][0] + ssum[t][1];
        }
    } else if (by == 0) {
        // ---------------- sup CE ----------------
        __shared__ float lp[1024];
        __shared__ float cep[4][2];
        if (t < 250) ((float4*)lp)[t] = ((const float4*)log_prior)[t];
        __syncthreads();
        float cen_acc = 0.0f, ced_acc = 0.0f;
        int rbase = bx * 64 + w * 16;
        for (int rr = 0; rr < 16; ++rr) {
            int row = rbase + rr;
            const float* lrow = logits + (size_t)row * NC_;
            const float4* lrow4 = (const float4*)lrow;
            float vals[16];
            float m = -1e30f;
            #pragma unroll
            for (int it = 0; it < 4; ++it) {
                int idx = it * 64 + l;
                float4 v4 = (idx < 250) ? lrow4[idx]
                                        : make_float4(-1e30f, -1e30f, -1e30f, -1e30f);
                float4 p4 = (idx < 250) ? ((const float4*)lp)[idx]
                                        : make_float4(0, 0, 0, 0);
                vals[it * 4 + 0] = v4.x + p4.x;
                vals[it * 4 + 1] = v4.y + p4.y;
                vals[it * 4 + 2] = v4.z + p4.z;
                vals[it * 4 + 3] = v4.w + p4.w;
                #pragma unroll
                for (int k = 0; k < 4; ++k) m = fmaxf(m, vals[it * 4 + k]);
            }
            #pragma unroll
            for (int msk = 1; msk < 64; msk <<= 1) m = fmaxf(m, __shfl_xor(m, msk, 64));
            float s1 = 0.0f, s20 = 0.0f;
            #pragma unroll
            for (int k = 0; k < 16; ++k) {
                float d = vals[k] - m;
                s1  += __expf(d);
                s20 += __expf(TEMP_INV * d);
            }
            #pragma unroll
            for (int msk = 1; msk < 64; msk <<= 1) {
                s1  += __shfl_xor(s1, msk, 64);
                s20 += __shfl_xor(s20, msk, 64);
            }
            if (l == 0) {
                int lab = labels[row];
                float vpos = lrow[lab] + lp[lab];
                float wt = class_weight[lab];
                cen_acc += wt * (m + __logf(s1) - vpos);
                ced_acc += wt;
                ws[WS_SUPM + row] = TEMP_INV * m;
                ws[WS_PS + (size_t)row * PCH + (PCH - 1)] = s20;
                ws[WS_PSUP + row] = TEMP_INV * vpos;
            }
        }
        if (l == 0) { cep[w][0] = cen_acc; cep[w][1] = ced_acc; }
        __syncthreads();
        if (t == 0) {
            ws[WS_CEPN + bx] = cep[0][0] + cep[1][0] + cep[2][0] + cep[3][0];
            ws[WS_CEPD + bx] = cep[0][1] + cep[1][1] + cep[2][1] + cep[3][1];
        }
    } else if (by <= 2) {
        // ---------------- gram via MFMA ----------------
        int g = (by - 1) * 64 + bx;            // 0..127
        int gr = g >> 3, gc = g & 7;
        int wm = w >> 1, wn = w & 1;
        int r0 = gr * 64 + wm * 32;
        int c0 = gc * 128 + wn * 64;
        int lr = l & 15, lg = l >> 4;
        int lk = lg * 8;

        const ushort* Af = B + (size_t)(r0 + lr) * D_ + lk;
        const ushort* Bf = B + (size_t)(c0 + lr) * D_ + lk;

        short8_t a[2][2], b[4][2];
        #pragma unroll
        for (int rf = 0; rf < 2; ++rf)
            #pragma unroll
            for (int ks = 0; ks < 2; ++ks)
                a[rf][ks] = *(const short8_t*)(Af + rf * 16 * D_ + ks * 32);
        #pragma unroll
        for (int cf = 0; cf < 4; ++cf)
            #pragma unroll
            for (int ks = 0; ks < 2; ++ks)
                b[cf][ks] = *(const short8_t*)(Bf + cf * 16 * D_ + ks * 32);

        f32x4 acc[2][4] = {};
        #pragma unroll
        for (int ks = 0; ks < 2; ++ks)
            #pragma unroll
            for (int rf = 0; rf < 2; ++rf)
                #pragma unroll
                for (int cf = 0; cf < 4; ++cf)
                    acc[rf][cf] = __builtin_amdgcn_mfma_f32_16x16x32_bf16(
                        a[rf][ks], b[cf][ks], acc[rf][cf], 0, 0, 0);

        float lsum = 0.0f, lmin = 1e30f;
        #pragma unroll
        for (int rf = 0; rf < 2; ++rf)
            #pragma unroll
            for (int cf = 0; cf < 4; ++cf)
                #pragma unroll
                for (int reg = 0; reg < 4; ++reg) {
                    int gi = r0 + rf * 16 + lg * 4 + reg;
                    int gj = c0 + cf * 16 + lr;
                    if (gi < NC_ && gj < NC_ && gi != gj) {
                        float d = sqrtf(fmaxf(2.0f - 2.0f * acc[rf][cf][reg], 1e-12f));
                        lsum += d;
                        lmin = fminf(lmin, d);
                    }
                }
        #pragma unroll
        for (int msk = 1; msk < 64; msk <<= 1) {
            lsum += __shfl_xor(lsum, msk, 64);
            lmin = fminf(lmin, __shfl_xor(lmin, msk, 64));
        }
        __shared__ float gs[4], gm[4];
        if (l == 0) { gs[w] = lsum; gm[w] = lmin; }
        __syncthreads();
        if (t == 0) {
            ws[WS_GS + g] = gs[0] + gs[1] + gs[2] + gs[3];
            ws[WS_GM + g] = fminf(fminf(gm[0], gm[1]), fminf(gm[2], gm[3]));
        }
    } else {
        // ---------------- stats partials ----------------
        int wid = bx * 4 + w;                  // 0..255
        float vf = 0.0f, vc = 0.0f, tacc = 0.0f;
        for (int i = wid; i < N_; i += 256) {
            float x = f[i * D_ + l];
            float c = cent[labels[i] * D_ + l];
            vf += x; vc += c; tacc += x * c;
        }
        #pragma unroll
        for (int msk = 32; msk >= 1; msk >>= 1) tacc += __shfl_xor(tacc, msk, 64);
        __shared__ float svf[4][64], svc[4][64], stp[4];
        svf[w][l] = vf; svc[w][l] = vc;
        if (l == 0) stp[w] = tacc;
        __syncthreads();
        if (w == 0) {
            ws[WS_VF + bx * 64 + l] = svf[0][l] + svf[1][l] + svf[2][l] + svf[3][l];
            ws[WS_VC + bx * 64 + l] = svc[0][l] + svc[1][l] + svc[2][l] + svc[3][l];
            if (l == 0) ws[WS_TP + bx] = stp[0] + stp[1] + stp[2] + stp[3];
        }
    }
}

// per-row merge -> per-block contrast partials
__global__ __launch_bounds__(256) void k_red(float* ws) {
    __shared__ float cb[4];
    int w = threadIdx.x >> 6, l = threadIdx.x & 63;
    int row = blockIdx.x * 4 + w;
    const float* pv = ws + WS_PS + (size_t)row * PCH;
    float s = pv[l];                       // chunks 0..63
    if (l < 8) s += pv[l + 64];            // chunks 64..71
    #pragma unroll
    for (int msk = 1; msk < 64; msk <<= 1) s += __shfl_xor(s, msk, 64);
    if (l == 0) {
        float msup = ws[WS_SUPM + row];
        float ssup = pv[PCH - 1];
        float M = fmaxf(M0, msup);
        float stot = s * __expf(M0 - M) + ssup * __expf(msup - M);
        float logS = __logf(stot + 1e-12f);
        float lp1 = ws[WS_PSUP + row] - M - logS;
        float lp2 = ws[WS_PCENT + row] * TEMP_INV - M - logS;
        cb[w] = (lp1 + 0.02f * lp2) / (1.02f + 1e-12f);
    }
    __syncthreads();
    if (threadIdx.x == 0)
        ws[WS_CSP + blockIdx.x] = cb[0] + cb[1] + cb[2] + cb[3];
}

// single-block reduce of all partials + closed-form S_W/S_B + final scalar
__global__ __launch_bounds__(256) void k_final(const float* __restrict__ ws,
                                               float* __restrict__ out) {
    int t = threadIdx.x, w = t >> 6, l = t & 63;
    float csum = 0.0f;
    #pragma unroll
    for (int k = 0; k < 4; ++k) csum += ws[WS_CSP + t + k * 256];
    float cen = 0, ced = 0, gsum = 0, gmin = 1e30f, vf = 0, vc = 0, tp = 0;
    if (t < 64) {
        cen = ws[WS_CEPN + t];
        ced = ws[WS_CEPD + t];
        tp  = ws[WS_TP + t];
        for (int b = 0; b < 64; ++b) {
            vf += ws[WS_VF + b * 64 + t];
            vc += ws[WS_VC + b * 64 + t];
        }
    }
    if (t < 128) { gsum = ws[WS_GS + t]; gmin = ws[WS_GM + t]; }
    float mu_d = vf * (1.0f / (float)N_);
    float vmu  = vc * mu_d;
    float mumu = mu_d * mu_d;
    #pragma unroll
    for (int m = 32; m >= 1; m >>= 1) {
        csum += __shfl_xor(csum, m, 64);
        cen  += __shfl_xor(cen, m, 64);
        ced  += __shfl_xor(ced, m, 64);
        gsum += __shfl_xor(gsum, m, 64);
        gmin = fminf(gmin, __shfl_xor(gmin, m, 64));
        vmu  += __shfl_xor(vmu, m, 64);
        mumu += __shfl_xor(mumu, m, 64);
        tp   += __shfl_xor(tp, m, 64);
    }
    __shared__ float red[4][8];
    if (l == 0) {
        red[w][0] = csum; red[w][1] = cen; red[w][2] = ced; red[w][3] = gsum;
        red[w][4] = gmin; red[w][5] = vmu; red[w][6] = mumu; red[w][7] = tp;
    }
    __syncthreads();
    if (t == 0) {
        float CSM = red[0][0] + red[1][0] + red[2][0] + red[3][0];
        float CEN = red[0][1] + red[1][1] + red[2][1] + red[3][1];
        float CED = red[0][2] + red[1][2] + red[2][2] + red[3][2];
        float GSM = red[0][3] + red[1][3] + red[2][3] + red[3][3];
        float GMN = fminf(fminf(red[0][4], red[1][4]), fminf(red[2][4], red[3][4]));
        float VMU = red[0][5] + red[1][5] + red[2][5] + red[3][5];
        float MUMU = red[0][6] + red[1][6] + red[2][6] + red[3][6];
        float T   = red[0][7] + red[1][7] + red[2][7] + red[3][7];
        float SW = 2.0f * (float)N_ - 2.0f * T;
        float SB = (float)N_ - 2.0f * VMU + (float)N_ * MUMU;
        float intra = SW / (float)N_;
        float fisher = SB / (SW + 1e-6f);
        float ce = CEN / CED;
        float contrast = -(CSM / (float)N_);
        float inter_mean = GSM / (float)(NC_ * (NC_ - 1));
        float reg = intra + 0.1f / (inter_mean + 1e-6f)
                  + 0.05f / (GMN + 1e-6f) + 0.1f / (fisher + 1e-6f);
        out[0] = ce + contrast + reg;
    }
}

extern "C" void kernel_launch(void* const* d_in, const int* in_sizes, int n_in,
                              void* d_out, int out_size, void* d_ws, size_t ws_size,
                              hipStream_t stream) {
    const float* feats        = (const float*)d_in[0];
    const float* logits       = (const float*)d_in[1];
    const int*   labels       = (const int*)d_in[2];
    const float* C            = (const float*)d_in[3];
    const float* queue        = (const float*)d_in[4];
    const float* log_prior    = (const float*)d_in[5];
    const float* class_weight = (const float*)d_in[6];
    float* ws  = (float*)d_ws;
    float* out = (float*)d_out;
    ushort* Bbf = (ushort*)(ws + WS_BBF);

    hipLaunchKernelGGL(k_prep,  dim3(2058),   dim3(256), 0, stream,
                       feats, C, queue, ws + WS_F, ws + WS_CENT, Bbf);
    hipLaunchKernelGGL(k_mega,  dim3(64, 76), dim3(256), 0, stream,
                       Bbf, logits, labels, log_prior, class_weight,
                       ws + WS_F, ws + WS_CENT, ws);
    hipLaunchKernelGGL(k_red,   dim3(N_/4),   dim3(256), 0, stream, ws);
    hipLaunchKernelGGL(k_final, dim3(1),      dim3(256), 0, stream, ws, out);
}

// Round 6
// 52.118 us; speedup vs baseline: 4.9468x; 1.0582x over previous
//
#include <hip/hip_runtime.h>
#include <math.h>

#define N_ 4096
#define D_ 64
#define NC_ 1000
#define KQ_ 8192
#define VCOLS 9192          // NC + KQ real columns
#define VPAD  9216          // 18*512 padded
#define NCG   18            // gemm col-groups of 512
#define PCH   19            // 18 gemm partials + 1 sup chunk
#define TEMP_INV 20.0f
#define M0 20.25f           // fixed softmax reference for gemm chunks (dots <= 1)
#define LOG2E 1.4426950408889634f
#define K2L  (TEMP_INV * LOG2E)
#define M0L  (M0 * LOG2E)

// workspace layout (float offsets)
#define WS_F     0
#define WS_CENT  (WS_F + N_*D_)
#define WS_SUPM  (WS_CENT + NC_*D_)
#define WS_PSUP  (WS_SUPM + N_)
#define WS_PCENT (WS_PSUP + N_)
#define WS_CEPN  (WS_PCENT + N_)     // 256 CE numerator partials
#define WS_CEPD  (WS_CEPN + 256)     // 256 CE denominator partials
#define WS_CSP   (WS_CEPD + 256)     // 256 contrast partials
#define WS_GS    (WS_CSP + 256)      // 128 gram dist-sum partials
#define WS_GM    (WS_GS + 128)       // 128 gram dist-min partials
#define WS_VF    (WS_GM + 128)       // 64 blocks x 64 dims: sum f
#define WS_VC    (WS_VF + 4096)      // 64 blocks x 64 dims: sum cent[label]
#define WS_TP    (WS_VC + 4096)      // 64: sum f.cent[label] partials
#define WS_PS    (WS_TP + 64)        // N*PCH chunk sums
#define WS_BBF   (WS_PS + N_*PCH)    // ushort[VPAD*64]

typedef __attribute__((ext_vector_type(8))) short short8_t;
typedef __attribute__((ext_vector_type(4))) float f32x4;

__device__ __forceinline__ ushort f2bf(float x) {
    union { float f; unsigned u; } v; v.f = x;
    unsigned r = (v.u + 0x7FFFu + ((v.u >> 16) & 1u)) >> 16;
    return (ushort)r;
}

// merged prep: norm_f rows (blocks 0..1023), norm_c cols (1024..1027),
// queue-tail bf16 (1028..2057)
__global__ __launch_bounds__(256) void k_prep(const float* __restrict__ feats,
                                              const float* __restrict__ C,
                                              const float* __restrict__ queue,
                                              float* __restrict__ f,
                                              float* __restrict__ cent,
                                              ushort* __restrict__ B) {
    int b = blockIdx.x;
    if (b < 1024) {
        int row  = b * 4 + (threadIdx.x >> 6);
        int lane = threadIdx.x & 63;
        float x = feats[row * D_ + lane];
        float ss = x * x;
        #pragma unroll
        for (int m = 32; m >= 1; m >>= 1) ss += __shfl_xor(ss, m, 64);
        float y = x / fmaxf(sqrtf(ss), 1e-12f);
        f[row * D_ + lane] = y;
        B[(size_t)(NC_ + row) * D_ + lane] = f2bf(y);
    } else if (b < 1028) {
        int c = (b - 1024) * 256 + threadIdx.x;
        if (c >= NC_) return;
        float v[D_];
        float ss = 0.0f;
        #pragma unroll
        for (int d = 0; d < D_; ++d) { float x = C[d * NC_ + c]; v[d] = x; ss += x * x; }
        float inv = 1.0f / fmaxf(sqrtf(ss), 1e-12f);
        #pragma unroll
        for (int d = 0; d < D_; ++d) {
            float y = v[d] * inv;
            cent[c * D_ + d] = y;
            B[(size_t)c * D_ + d] = f2bf(y);
        }
    } else {
        int t = (b - 1028) * 256 + threadIdx.x;   // over (4096+24)*64
        if (t >= (KQ_ - N_ + 24) * D_) return;
        int r = t >> 6, d = t & 63;
        ushort o = 0;
        if (r < KQ_ - N_) o = f2bf(queue[(size_t)(N_ + r) * D_ + d]);
        B[(size_t)(NC_ + N_ + r) * D_ + d] = o;
    }
}

// mega kernel, grid (64, 25):
//   by 0..3  : sup CE (block = 16 rows, wave = 4 rows)    [dispatched first]
//   by 4..5  : gram via MFMA (128 blocks)
//   by 6     : stats partials
//   by 7..24 : gemm col-group cg=by-7 (64-row x 512-col strip per block)
__global__ __launch_bounds__(256) void k_mega(const ushort* __restrict__ B,
                                              const float* __restrict__ logits,
                                              const int* __restrict__ labels,
                                              const float* __restrict__ log_prior,
                                              const float* __restrict__ class_weight,
                                              const float* __restrict__ f,
                                              const float* __restrict__ cent,
                                              float* __restrict__ ws) {
    int t = threadIdx.x;
    int l = t & 63, w = t >> 6;
    int bx = blockIdx.x, by = blockIdx.y;

    if (by >= 7) {
        // ---------------- GEMM strip: 64 rows x 512 cols ----------------
        int cg = by - 7;
        int wm = w >> 1, wn = w & 1;
        int r0 = bx * 64 + wm * 32;
        int lr = l & 15, lg = l >> 4;
        int lk = lg * 8;

        const ushort* Af = B + (size_t)(NC_ + r0 + lr) * D_ + lk;
        short8_t a[2][2];
        #pragma unroll
        for (int rf = 0; rf < 2; ++rf)
            #pragma unroll
            for (int ks = 0; ks < 2; ++ks)
                a[rf][ks] = *(const short8_t*)(Af + rf * 16 * D_ + ks * 32);

        int lab[2][4];
        if (cg < 2) {
            #pragma unroll
            for (int rf = 0; rf < 2; ++rf)
                #pragma unroll
                for (int reg = 0; reg < 4; ++reg)
                    lab[rf][reg] = labels[r0 + rf * 16 + lg * 4 + reg];
        }

        float se[2][4] = {};
        #pragma unroll
        for (int ci = 0; ci < 4; ++ci) {
            int c0 = cg * 512 + ci * 128 + wn * 64;
            const ushort* Bf = B + (size_t)(c0 + lr) * D_ + lk;
            short8_t b[4][2];
            #pragma unroll
            for (int cf = 0; cf < 4; ++cf)
                #pragma unroll
                for (int ks = 0; ks < 2; ++ks)
                    b[cf][ks] = *(const short8_t*)(Bf + cf * 16 * D_ + ks * 32);

            f32x4 acc[2][4] = {};
            #pragma unroll
            for (int ks = 0; ks < 2; ++ks)
                #pragma unroll
                for (int rf = 0; rf < 2; ++rf)
                    #pragma unroll
                    for (int cf = 0; cf < 4; ++cf)
                        acc[rf][cf] = __builtin_amdgcn_mfma_f32_16x16x32_bf16(
                            a[rf][ks], b[cf][ks], acc[rf][cf], 0, 0, 0);

            if (cg < 2) {   // chunk cols < 1024: may contain label columns
                #pragma unroll
                for (int rf = 0; rf < 2; ++rf)
                    #pragma unroll
                    for (int reg = 0; reg < 4; ++reg) {
                        #pragma unroll
                        for (int cf = 0; cf < 4; ++cf) {
                            int col = c0 + cf * 16 + lr;
                            if (col == lab[rf][reg])
                                ws[WS_PCENT + r0 + rf * 16 + lg * 4 + reg] =
                                    acc[rf][cf][reg];
                        }
                    }
            }

            // accumulate sumexp (fixed ref M0; pad rows give exp(-M0) ~ 2e-9)
            #pragma unroll
            for (int rf = 0; rf < 2; ++rf)
                #pragma unroll
                for (int cf = 0; cf < 4; ++cf)
                    #pragma unroll
                    for (int reg = 0; reg < 4; ++reg)
                        se[rf][reg] += __builtin_amdgcn_exp2f(
                            fmaf(acc[rf][cf][reg], K2L, -M0L));
        }

        __shared__ float ssum[64][2];
        #pragma unroll
        for (int rf = 0; rf < 2; ++rf)
            #pragma unroll
            for (int reg = 0; reg < 4; ++reg) {
                float v = se[rf][reg];
                #pragma unroll
                for (int msk = 1; msk < 16; msk <<= 1)
                    v += __shfl_xor(v, msk, 64);
                if (lr == 0) ssum[wm * 32 + rf * 16 + lg * 4 + reg][wn] = v;
            }
        __syncthreads();
        if (t < 64)
            ws[WS_PS + (size_t)(bx * 64 + t) * PCH + cg] = ssum[t][0] + ssum[t][1];
    } else if (by < 4) {
        // ---------------- sup CE: 16 rows/block, 4 rows/wave ----------------
        __shared__ float lp[1024];
        __shared__ float cep[4][2];
        if (t < 250) ((float4*)lp)[t] = ((const float4*)log_prior)[t];
        __syncthreads();
        float cen_acc = 0.0f, ced_acc = 0.0f;
        int rbase = bx * 64 + by * 16 + w * 4;
        for (int rr = 0; rr < 4; ++rr) {
            int row = rbase + rr;
            const float* lrow = logits + (size_t)row * NC_;
            const float4* lrow4 = (const float4*)lrow;
            float vals[16];
            float m = -1e30f;
            #pragma unroll
            for (int it = 0; it < 4; ++it) {
                int idx = it * 64 + l;
                float4 v4 = (idx < 250) ? lrow4[idx]
                                        : make_float4(-1e30f, -1e30f, -1e30f, -1e30f);
                float4 p4 = (idx < 250) ? ((const float4*)lp)[idx]
                                        : make_float4(0, 0, 0, 0);
                vals[it * 4 + 0] = v4.x + p4.x;
                vals[it * 4 + 1] = v4.y + p4.y;
                vals[it * 4 + 2] = v4.z + p4.z;
                vals[it * 4 + 3] = v4.w + p4.w;
                #pragma unroll
                for (int k = 0; k < 4; ++k) m = fmaxf(m, vals[it * 4 + k]);
            }
            #pragma unroll
            for (int msk = 1; msk < 64; msk <<= 1) m = fmaxf(m, __shfl_xor(m, msk, 64));
            float s1 = 0.0f, s20 = 0.0f;
            #pragma unroll
            for (int k = 0; k < 16; ++k) {
                float d = vals[k] - m;
                s1  += __builtin_amdgcn_exp2f(d * LOG2E);
                s20 += __builtin_amdgcn_exp2f(d * K2L);
            }
            #pragma unroll
            for (int msk = 1; msk < 64; msk <<= 1) {
                s1  += __shfl_xor(s1, msk, 64);
                s20 += __shfl_xor(s20, msk, 64);
            }
            if (l == 0) {
                int lab = labels[row];
                float vpos = lrow[lab] + lp[lab];
                float wt = class_weight[lab];
                cen_acc += wt * (m + __logf(s1) - vpos);
                ced_acc += wt;
                ws[WS_SUPM + row] = TEMP_INV * m;
                ws[WS_PS + (size_t)row * PCH + (PCH - 1)] = s20;
                ws[WS_PSUP + row] = TEMP_INV * vpos;
            }
        }
        if (l == 0) { cep[w][0] = cen_acc; cep[w][1] = ced_acc; }
        __syncthreads();
        if (t == 0) {
            int sblk = by * 64 + bx;
            ws[WS_CEPN + sblk] = cep[0][0] + cep[1][0] + cep[2][0] + cep[3][0];
            ws[WS_CEPD + sblk] = cep[0][1] + cep[1][1] + cep[2][1] + cep[3][1];
        }
    } else if (by <= 5) {
        // ---------------- gram via MFMA ----------------
        int g = (by - 4) * 64 + bx;            // 0..127
        int gr = g >> 3, gc = g & 7;
        int wm = w >> 1, wn = w & 1;
        int r0 = gr * 64 + wm * 32;
        int c0 = gc * 128 + wn * 64;
        int lr = l & 15, lg = l >> 4;
        int lk = lg * 8;

        const ushort* Af = B + (size_t)(r0 + lr) * D_ + lk;
        const ushort* Bf = B + (size_t)(c0 + lr) * D_ + lk;

        short8_t a[2][2], b[4][2];
        #pragma unroll
        for (int rf = 0; rf < 2; ++rf)
            #pragma unroll
            for (int ks = 0; ks < 2; ++ks)
                a[rf][ks] = *(const short8_t*)(Af + rf * 16 * D_ + ks * 32);
        #pragma unroll
        for (int cf = 0; cf < 4; ++cf)
            #pragma unroll
            for (int ks = 0; ks < 2; ++ks)
                b[cf][ks] = *(const short8_t*)(Bf + cf * 16 * D_ + ks * 32);

        f32x4 acc[2][4] = {};
        #pragma unroll
        for (int ks = 0; ks < 2; ++ks)
            #pragma unroll
            for (int rf = 0; rf < 2; ++rf)
                #pragma unroll
                for (int cf = 0; cf < 4; ++cf)
                    acc[rf][cf] = __builtin_amdgcn_mfma_f32_16x16x32_bf16(
                        a[rf][ks], b[cf][ks], acc[rf][cf], 0, 0, 0);

        float lsum = 0.0f, lmin = 1e30f;
        #pragma unroll
        for (int rf = 0; rf < 2; ++rf)
            #pragma unroll
            for (int cf = 0; cf < 4; ++cf)
                #pragma unroll
                for (int reg = 0; reg < 4; ++reg) {
                    int gi = r0 + rf * 16 + lg * 4 + reg;
                    int gj = c0 + cf * 16 + lr;
                    if (gi < NC_ && gj < NC_ && gi != gj) {
                        float d = sqrtf(fmaxf(2.0f - 2.0f * acc[rf][cf][reg], 1e-12f));
                        lsum += d;
                        lmin = fminf(lmin, d);
                    }
                }
        #pragma unroll
        for (int msk = 1; msk < 64; msk <<= 1) {
            lsum += __shfl_xor(lsum, msk, 64);
            lmin = fminf(lmin, __shfl_xor(lmin, msk, 64));
        }
        __shared__ float gs[4], gm[4];
        if (l == 0) { gs[w] = lsum; gm[w] = lmin; }
        __syncthreads();
        if (t == 0) {
            ws[WS_GS + g] = gs[0] + gs[1] + gs[2] + gs[3];
            ws[WS_GM + g] = fminf(fminf(gm[0], gm[1]), fminf(gm[2], gm[3]));
        }
    } else {
        // ---------------- stats partials ----------------
        int wid = bx * 4 + w;                  // 0..255
        float vf = 0.0f, vc = 0.0f, tacc = 0.0f;
        for (int i = wid; i < N_; i += 256) {
            float x = f[i * D_ + l];
            float c = cent[labels[i] * D_ + l];
            vf += x; vc += c; tacc += x * c;
        }
        #pragma unroll
        for (int msk = 32; msk >= 1; msk >>= 1) tacc += __shfl_xor(tacc, msk, 64);
        __shared__ float svf[4][64], svc[4][64], stp[4];
        svf[w][l] = vf; svc[w][l] = vc;
        if (l == 0) stp[w] = tacc;
        __syncthreads();
        if (w == 0) {
            ws[WS_VF + bx * 64 + l] = svf[0][l] + svf[1][l] + svf[2][l] + svf[3][l];
            ws[WS_VC + bx * 64 + l] = svc[0][l] + svc[1][l] + svc[2][l] + svc[3][l];
            if (l == 0) ws[WS_TP + bx] = stp[0] + stp[1] + stp[2] + stp[3];
        }
    }
}

// per-row merge -> per-block contrast partials; 256 blocks, 4 rows/wave
__global__ __launch_bounds__(256) void k_red(float* ws) {
    __shared__ float cb[4];
    int w = threadIdx.x >> 6, l = threadIdx.x & 63;
    float cacc = 0.0f;
    for (int rr = 0; rr < 4; ++rr) {
        int row = blockIdx.x * 16 + w * 4 + rr;
        const float* pv = ws + WS_PS + (size_t)row * PCH;
        float s = (l < NCG) ? pv[l] : 0.0f;
        #pragma unroll
        for (int msk = 1; msk < 64; msk <<= 1) s += __shfl_xor(s, msk, 64);
        if (l == 0) {
            float msup = ws[WS_SUPM + row];
            float ssup = pv[PCH - 1];
            float M = fmaxf(M0, msup);
            float stot = s * __builtin_amdgcn_exp2f((M0 - M) * LOG2E)
                       + ssup * __builtin_amdgcn_exp2f((msup - M) * LOG2E);
            float logS = __logf(stot + 1e-12f);
            float lp1 = ws[WS_PSUP + row] - M - logS;
            float lp2 = ws[WS_PCENT + row] * TEMP_INV - M - logS;
            cacc += (lp1 + 0.02f * lp2) / (1.02f + 1e-12f);
        }
    }
    if (l == 0) cb[w] = cacc;
    __syncthreads();
    if (threadIdx.x == 0)
        ws[WS_CSP + blockIdx.x] = cb[0] + cb[1] + cb[2] + cb[3];
}

// single-block reduce of all partials + closed-form S_W/S_B + final scalar
__global__ __launch_bounds__(256) void k_final(const float* __restrict__ ws,
                                               float* __restrict__ out) {
    int t = threadIdx.x, w = t >> 6, l = t & 63;
    float csum = ws[WS_CSP + t];
    float cen  = ws[WS_CEPN + t];
    float ced  = ws[WS_CEPD + t];
    float gsum = 0, gmin = 1e30f, vf = 0, vc = 0, tp = 0;
    if (t < 64) {
        tp = ws[WS_TP + t];
        for (int b = 0; b < 64; ++b) {
            vf += ws[WS_VF + b * 64 + t];
            vc += ws[WS_VC + b * 64 + t];
        }
    }
    if (t < 128) { gsum = ws[WS_GS + t]; gmin = ws[WS_GM + t]; }
    float mu_d = vf * (1.0f / (float)N_);
    float vmu  = vc * mu_d;
    float mumu = mu_d * mu_d;
    #pragma unroll
    for (int m = 32; m >= 1; m >>= 1) {
        csum += __shfl_xor(csum, m, 64);
        cen  += __shfl_xor(cen, m, 64);
        ced  += __shfl_xor(ced, m, 64);
        gsum += __shfl_xor(gsum, m, 64);
        gmin = fminf(gmin, __shfl_xor(gmin, m, 64));
        vmu  += __shfl_xor(vmu, m, 64);
        mumu += __shfl_xor(mumu, m, 64);
        tp   += __shfl_xor(tp, m, 64);
    }
    __shared__ float red[4][8];
    if (l == 0) {
        red[w][0] = csum; red[w][1] = cen; red[w][2] = ced; red[w][3] = gsum;
        red[w][4] = gmin; red[w][5] = vmu; red[w][6] = mumu; red[w][7] = tp;
    }
    __syncthreads();
    if (t == 0) {
        float CSM = red[0][0] + red[1][0] + red[2][0] + red[3][0];
        float CEN = red[0][1] + red[1][1] + red[2][1] + red[3][1];
        float CED = red[0][2] + red[1][2] + red[2][2] + red[3][2];
        float GSM = red[0][3] + red[1][3] + red[2][3] + red[3][3];
        float GMN = fminf(fminf(red[0][4], red[1][4]), fminf(red[2][4], red[3][4]));
        float VMU = red[0][5] + red[1][5] + red[2][5] + red[3][5];
        float MUMU = red[0][6] + red[1][6] + red[2][6] + red[3][6];
        float T   = red[0][7] + red[1][7] + red[2][7] + red[3][7];
        float SW = 2.0f * (float)N_ - 2.0f * T;
        float SB = (float)N_ - 2.0f * VMU + (float)N_ * MUMU;
        float intra = SW / (float)N_;
        float fisher = SB / (SW + 1e-6f);
        float ce = CEN / CED;
        float contrast = -(CSM / (float)N_);
        float inter_mean = GSM / (float)(NC_ * (NC_ - 1));
        float reg = intra + 0.1f / (inter_mean + 1e-6f)
                  + 0.05f / (GMN + 1e-6f) + 0.1f / (fisher + 1e-6f);
        out[0] = ce + contrast + reg;
    }
}

extern "C" void kernel_launch(void* const* d_in, const int* in_sizes, int n_in,
                              void* d_out, int out_size, void* d_ws, size_t ws_size,
                              hipStream_t stream) {
    const float* feats        = (const float*)d_in[0];
    const float* logits       = (const float*)d_in[1];
    const int*   labels       = (const int*)d_in[2];
    const float* C            = (const float*)d_in[3];
    const float* queue        = (const float*)d_in[4];
    const float* log_prior    = (const float*)d_in[5];
    const float* class_weight = (const float*)d_in[6];
    float* ws  = (float*)d_ws;
    float* out = (float*)d_out;
    ushort* Bbf = (ushort*)(ws + WS_BBF);

    hipLaunchKernelGGL(k_prep,  dim3(2058),   dim3(256), 0, stream,
                       feats, C, queue, ws + WS_F, ws + WS_CENT, Bbf);
    hipLaunchKernelGGL(k_mega,  dim3(64, 25), dim3(256), 0, stream,
                       Bbf, logits, labels, log_prior, class_weight,
                       ws + WS_F, ws + WS_CENT, ws);
    hipLaunchKernelGGL(k_red,   dim3(256),    dim3(256), 0, stream, ws);
    hipLaunchKernelGGL(k_final, dim3(1),      dim3(256), 0, stream, ws, out);
}

// Round 7
// 51.390 us; speedup vs baseline: 5.0169x; 1.0142x over previous
//
#include <hip/hip_runtime.h>
#include <math.h>

#define N_ 4096
#define D_ 64
#define NC_ 1000
#define KQ_ 8192
#define VCOLS 9192          // NC + KQ real columns
#define VPAD  9216          // 18*512 padded
#define NCG   18            // gemm col-groups of 512
#define PCH   19            // 18 gemm partials + 1 sup chunk
#define TEMP_INV 20.0f
#define M0 20.25f           // fixed softmax reference for gemm chunks (dots <= 1)
#define LOG2E 1.4426950408889634f
#define K2L  (TEMP_INV * LOG2E)
#define M0L  (M0 * LOG2E)

// workspace layout (float offsets)
#define WS_F     0
#define WS_CENT  (WS_F + N_*D_)
#define WS_SUPM  (WS_CENT + NC_*D_)
#define WS_PSUP  (WS_SUPM + N_)
#define WS_PCENT (WS_PSUP + N_)
#define WS_CEPN  (WS_PCENT + N_)     // 256 CE numerator partials
#define WS_CEPD  (WS_CEPN + 256)     // 256 CE denominator partials
#define WS_CSP   (WS_CEPD + 256)     // 256 contrast partials
#define WS_GS    (WS_CSP + 256)      // 128 gram dist-sum partials
#define WS_GM    (WS_GS + 128)       // 128 gram dist-min partials
#define WS_VF    (WS_GM + 128)       // 64 blocks x 64 dims: sum f
#define WS_VC    (WS_VF + 4096)      // 64 blocks x 64 dims: sum cent[label]
#define WS_TP    (WS_VC + 4096)      // 64: sum f.cent[label] partials
#define WS_PS    (WS_TP + 64)        // N*PCH chunk sums
#define WS_BBF   (WS_PS + N_*PCH)    // ushort[VPAD*64]

typedef __attribute__((ext_vector_type(8))) short short8_t;
typedef __attribute__((ext_vector_type(4))) float f32x4;

__device__ __forceinline__ ushort f2bf(float x) {
    union { float f; unsigned u; } v; v.f = x;
    unsigned r = (v.u + 0x7FFFu + ((v.u >> 16) & 1u)) >> 16;
    return (ushort)r;
}

__device__ __forceinline__ void loadB(const ushort* __restrict__ Bf, int ci,
                                      short8_t dst[4][2]) {
    #pragma unroll
    for (int cf = 0; cf < 4; ++cf)
        #pragma unroll
        for (int ks = 0; ks < 2; ++ks)
            dst[cf][ks] = *(const short8_t*)(Bf + (size_t)(ci * 128 + cf * 16) * D_
                                             + ks * 32);
}

__device__ __forceinline__ void gemm_tile(const short8_t a[2][2],
                                          const short8_t b[4][2],
                                          int c0, bool doext, const int lab[2][4],
                                          int r0, int lg, int lr,
                                          float se[2][4], float* __restrict__ ws) {
    f32x4 acc[2][4] = {};
    #pragma unroll
    for (int ks = 0; ks < 2; ++ks)
        #pragma unroll
        for (int rf = 0; rf < 2; ++rf)
            #pragma unroll
            for (int cf = 0; cf < 4; ++cf)
                acc[rf][cf] = __builtin_amdgcn_mfma_f32_16x16x32_bf16(
                    a[rf][ks], b[cf][ks], acc[rf][cf], 0, 0, 0);
    if (doext) {
        #pragma unroll
        for (int rf = 0; rf < 2; ++rf)
            #pragma unroll
            for (int reg = 0; reg < 4; ++reg) {
                #pragma unroll
                for (int cf = 0; cf < 4; ++cf) {
                    int col = c0 + cf * 16 + lr;
                    if (col == lab[rf][reg])
                        ws[WS_PCENT + r0 + rf * 16 + lg * 4 + reg] = acc[rf][cf][reg];
                }
            }
    }
    #pragma unroll
    for (int rf = 0; rf < 2; ++rf)
        #pragma unroll
        for (int cf = 0; cf < 4; ++cf)
            #pragma unroll
            for (int reg = 0; reg < 4; ++reg)
                se[rf][reg] += __builtin_amdgcn_exp2f(
                    fmaf(acc[rf][cf][reg], K2L, -M0L));
}

// merged prep: norm_f rows (blocks 0..1023), norm_c cols (1024..1027),
// queue-tail bf16 (1028..2057)
__global__ __launch_bounds__(256) void k_prep(const float* __restrict__ feats,
                                              const float* __restrict__ C,
                                              const float* __restrict__ queue,
                                              float* __restrict__ f,
                                              float* __restrict__ cent,
                                              ushort* __restrict__ B) {
    int b = blockIdx.x;
    if (b < 1024) {
        int row  = b * 4 + (threadIdx.x >> 6);
        int lane = threadIdx.x & 63;
        float x = feats[row * D_ + lane];
        float ss = x * x;
        #pragma unroll
        for (int m = 32; m >= 1; m >>= 1) ss += __shfl_xor(ss, m, 64);
        float y = x / fmaxf(sqrtf(ss), 1e-12f);
        f[row * D_ + lane] = y;
        B[(size_t)(NC_ + row) * D_ + lane] = f2bf(y);
    } else if (b < 1028) {
        int c = (b - 1024) * 256 + threadIdx.x;
        if (c >= NC_) return;
        float v[D_];
        float ss = 0.0f;
        #pragma unroll
        for (int d = 0; d < D_; ++d) { float x = C[d * NC_ + c]; v[d] = x; ss += x * x; }
        float inv = 1.0f / fmaxf(sqrtf(ss), 1e-12f);
        #pragma unroll
        for (int d = 0; d < D_; ++d) {
            float y = v[d] * inv;
            cent[c * D_ + d] = y;
            B[(size_t)c * D_ + d] = f2bf(y);
        }
    } else {
        int t = (b - 1028) * 256 + threadIdx.x;   // over (4096+24)*64
        if (t >= (KQ_ - N_ + 24) * D_) return;
        int r = t >> 6, d = t & 63;
        ushort o = 0;
        if (r < KQ_ - N_) o = f2bf(queue[(size_t)(N_ + r) * D_ + d]);
        B[(size_t)(NC_ + N_ + r) * D_ + d] = o;
    }
}

// mega kernel, grid (64, 25):
//   by 0..3  : sup CE (block = 16 rows, wave = 4 rows)
//   by 4..5  : gram via MFMA (128 blocks)
//   by 6     : stats partials
//   by 7..24 : gemm col-group cg=by-7 (64-row x 512-col strip, SW-pipelined)
__global__ __launch_bounds__(256, 2) void k_mega(const ushort* __restrict__ B,
                                              const float* __restrict__ logits,
                                              const int* __restrict__ labels,
                                              const float* __restrict__ log_prior,
                                              const float* __restrict__ class_weight,
                                              const float* __restrict__ f,
                                              const float* __restrict__ cent,
                                              float* __restrict__ ws) {
    int t = threadIdx.x;
    int l = t & 63, w = t >> 6;
    int bx = blockIdx.x, by = blockIdx.y;

    if (by >= 7) {
        // ---------------- GEMM strip: 64 rows x 512 cols, 2-deep pipeline ----
        int cg = by - 7;
        int wm = w >> 1, wn = w & 1;
        int r0 = bx * 64 + wm * 32;
        int lr = l & 15, lg = l >> 4;
        int lk = lg * 8;

        const ushort* Af = B + (size_t)(NC_ + r0 + lr) * D_ + lk;
        short8_t a[2][2];
        #pragma unroll
        for (int rf = 0; rf < 2; ++rf)
            #pragma unroll
            for (int ks = 0; ks < 2; ++ks)
                a[rf][ks] = *(const short8_t*)(Af + rf * 16 * D_ + ks * 32);

        int lab[2][4];
        bool doext = (cg < 2);
        if (doext) {
            #pragma unroll
            for (int rf = 0; rf < 2; ++rf)
                #pragma unroll
                for (int reg = 0; reg < 4; ++reg)
                    lab[rf][reg] = labels[r0 + rf * 16 + lg * 4 + reg];
        }

        const ushort* Bf = B + (size_t)(cg * 512 + wn * 64 + lr) * D_ + lk;
        int cbase = cg * 512 + wn * 64;

        short8_t b0[4][2], b1[4][2];
        float se[2][4] = {};

        loadB(Bf, 0, b0);
        loadB(Bf, 1, b1);
        gemm_tile(a, b0, cbase + 0 * 128, doext, lab, r0, lg, lr, se, ws);
        loadB(Bf, 2, b0);
        gemm_tile(a, b1, cbase + 1 * 128, doext, lab, r0, lg, lr, se, ws);
        loadB(Bf, 3, b1);
        gemm_tile(a, b0, cbase + 2 * 128, doext, lab, r0, lg, lr, se, ws);
        gemm_tile(a, b1, cbase + 3 * 128, doext, lab, r0, lg, lr, se, ws);

        __shared__ float ssum[64][2];
        #pragma unroll
        for (int rf = 0; rf < 2; ++rf)
            #pragma unroll
            for (int reg = 0; reg < 4; ++reg) {
                float v = se[rf][reg];
                #pragma unroll
                for (int msk = 1; msk < 16; msk <<= 1)
                    v += __shfl_xor(v, msk, 64);
                if (lr == 0) ssum[wm * 32 + rf * 16 + lg * 4 + reg][wn] = v;
            }
        __syncthreads();
        if (t < 64)
            ws[WS_PS + (size_t)(bx * 64 + t) * PCH + cg] = ssum[t][0] + ssum[t][1];
    } else if (by < 4) {
        // ---------------- sup CE: 16 rows/block, 4 rows/wave ----------------
        __shared__ float lp[1024];
        __shared__ float cep[4][2];
        if (t < 250) ((float4*)lp)[t] = ((const float4*)log_prior)[t];
        __syncthreads();
        float cen_acc = 0.0f, ced_acc = 0.0f;
        int rbase = bx * 64 + by * 16 + w * 4;
        for (int rr = 0; rr < 4; ++rr) {
            int row = rbase + rr;
            const float* lrow = logits + (size_t)row * NC_;
            const float4* lrow4 = (const float4*)lrow;
            float vals[16];
            float m = -1e30f;
            #pragma unroll
            for (int it = 0; it < 4; ++it) {
                int idx = it * 64 + l;
                float4 v4 = (idx < 250) ? lrow4[idx]
                                        : make_float4(-1e30f, -1e30f, -1e30f, -1e30f);
                float4 p4 = (idx < 250) ? ((const float4*)lp)[idx]
                                        : make_float4(0, 0, 0, 0);
                vals[it * 4 + 0] = v4.x + p4.x;
                vals[it * 4 + 1] = v4.y + p4.y;
                vals[it * 4 + 2] = v4.z + p4.z;
                vals[it * 4 + 3] = v4.w + p4.w;
                #pragma unroll
                for (int k = 0; k < 4; ++k) m = fmaxf(m, vals[it * 4 + k]);
            }
            #pragma unroll
            for (int msk = 1; msk < 64; msk <<= 1) m = fmaxf(m, __shfl_xor(m, msk, 64));
            float s1 = 0.0f, s20 = 0.0f;
            #pragma unroll
            for (int k = 0; k < 16; ++k) {
                float d = vals[k] - m;
                s1  += __builtin_amdgcn_exp2f(d * LOG2E);
                s20 += __builtin_amdgcn_exp2f(d * K2L);
            }
            #pragma unroll
            for (int msk = 1; msk < 64; msk <<= 1) {
                s1  += __shfl_xor(s1, msk, 64);
                s20 += __shfl_xor(s20, msk, 64);
            }
            if (l == 0) {
                int lab = labels[row];
                float vpos = lrow[lab] + lp[lab];
                float wt = class_weight[lab];
                cen_acc += wt * (m + __logf(s1) - vpos);
                ced_acc += wt;
                ws[WS_SUPM + row] = TEMP_INV * m;
                ws[WS_PS + (size_t)row * PCH + (PCH - 1)] = s20;
                ws[WS_PSUP + row] = TEMP_INV * vpos;
            }
        }
        if (l == 0) { cep[w][0] = cen_acc; cep[w][1] = ced_acc; }
        __syncthreads();
        if (t == 0) {
            int sblk = by * 64 + bx;
            ws[WS_CEPN + sblk] = cep[0][0] + cep[1][0] + cep[2][0] + cep[3][0];
            ws[WS_CEPD + sblk] = cep[0][1] + cep[1][1] + cep[2][1] + cep[3][1];
        }
    } else if (by <= 5) {
        // ---------------- gram via MFMA ----------------
        int g = (by - 4) * 64 + bx;            // 0..127
        int gr = g >> 3, gc = g & 7;
        int wm = w >> 1, wn = w & 1;
        int r0 = gr * 64 + wm * 32;
        int c0 = gc * 128 + wn * 64;
        int lr = l & 15, lg = l >> 4;
        int lk = lg * 8;

        const ushort* Af = B + (size_t)(r0 + lr) * D_ + lk;
        const ushort* Bf = B + (size_t)(c0 + lr) * D_ + lk;

        short8_t a[2][2], b[4][2];
        #pragma unroll
        for (int rf = 0; rf < 2; ++rf)
            #pragma unroll
            for (int ks = 0; ks < 2; ++ks)
                a[rf][ks] = *(const short8_t*)(Af + rf * 16 * D_ + ks * 32);
        #pragma unroll
        for (int cf = 0; cf < 4; ++cf)
            #pragma unroll
            for (int ks = 0; ks < 2; ++ks)
                b[cf][ks] = *(const short8_t*)(Bf + cf * 16 * D_ + ks * 32);

        f32x4 acc[2][4] = {};
        #pragma unroll
        for (int ks = 0; ks < 2; ++ks)
            #pragma unroll
            for (int rf = 0; rf < 2; ++rf)
                #pragma unroll
                for (int cf = 0; cf < 4; ++cf)
                    acc[rf][cf] = __builtin_amdgcn_mfma_f32_16x16x32_bf16(
                        a[rf][ks], b[cf][ks], acc[rf][cf], 0, 0, 0);

        float lsum = 0.0f, lmin = 1e30f;
        #pragma unroll
        for (int rf = 0; rf < 2; ++rf)
            #pragma unroll
            for (int cf = 0; cf < 4; ++cf)
                #pragma unroll
                for (int reg = 0; reg < 4; ++reg) {
                    int gi = r0 + rf * 16 + lg * 4 + reg;
                    int gj = c0 + cf * 16 + lr;
                    if (gi < NC_ && gj < NC_ && gi != gj) {
                        float d = sqrtf(fmaxf(2.0f - 2.0f * acc[rf][cf][reg], 1e-12f));
                        lsum += d;
                        lmin = fminf(lmin, d);
                    }
                }
        #pragma unroll
        for (int msk = 1; msk < 64; msk <<= 1) {
            lsum += __shfl_xor(lsum, msk, 64);
            lmin = fminf(lmin, __shfl_xor(lmin, msk, 64));
        }
        __shared__ float gs[4], gm[4];
        if (l == 0) { gs[w] = lsum; gm[w] = lmin; }
        __syncthreads();
        if (t == 0) {
            ws[WS_GS + g] = gs[0] + gs[1] + gs[2] + gs[3];
            ws[WS_GM + g] = fminf(fminf(gm[0], gm[1]), fminf(gm[2], gm[3]));
        }
    } else {
        // ---------------- stats partials ----------------
        int wid = bx * 4 + w;                  // 0..255
        float vf = 0.0f, vc = 0.0f, tacc = 0.0f;
        for (int i = wid; i < N_; i += 256) {
            float x = f[i * D_ + l];
            float c = cent[labels[i] * D_ + l];
            vf += x; vc += c; tacc += x * c;
        }
        #pragma unroll
        for (int msk = 32; msk >= 1; msk >>= 1) tacc += __shfl_xor(tacc, msk, 64);
        __shared__ float svf[4][64], svc[4][64], stp[4];
        svf[w][l] = vf; svc[w][l] = vc;
        if (l == 0) stp[w] = tacc;
        __syncthreads();
        if (w == 0) {
            ws[WS_VF + bx * 64 + l] = svf[0][l] + svf[1][l] + svf[2][l] + svf[3][l];
            ws[WS_VC + bx * 64 + l] = svc[0][l] + svc[1][l] + svc[2][l] + svc[3][l];
            if (l == 0) ws[WS_TP + bx] = stp[0] + stp[1] + stp[2] + stp[3];
        }
    }
}

// per-row merge -> per-block contrast partials; 256 blocks, 4 rows/wave
__global__ __launch_bounds__(256) void k_red(float* ws) {
    __shared__ float cb[4];
    int w = threadIdx.x >> 6, l = threadIdx.x & 63;
    float cacc = 0.0f;
    for (int rr = 0; rr < 4; ++rr) {
        int row = blockIdx.x * 16 + w * 4 + rr;
        const float* pv = ws + WS_PS + (size_t)row * PCH;
        float s = (l < NCG) ? pv[l] : 0.0f;
        #pragma unroll
        for (int msk = 1; msk < 64; msk <<= 1) s += __shfl_xor(s, msk, 64);
        if (l == 0) {
            float msup = ws[WS_SUPM + row];
            float ssup = pv[PCH - 1];
            float M = fmaxf(M0, msup);
            float stot = s * __builtin_amdgcn_exp2f((M0 - M) * LOG2E)
                       + ssup * __builtin_amdgcn_exp2f((msup - M) * LOG2E);
            float logS = __logf(stot + 1e-12f);
            float lp1 = ws[WS_PSUP + row] - M - logS;
            float lp2 = ws[WS_PCENT + row] * TEMP_INV - M - logS;
            cacc += (lp1 + 0.02f * lp2) / (1.02f + 1e-12f);
        }
    }
    if (l == 0) cb[w] = cacc;
    __syncthreads();
    if (threadIdx.x == 0)
        ws[WS_CSP + blockIdx.x] = cb[0] + cb[1] + cb[2] + cb[3];
}

// single-block reduce of all partials + closed-form S_W/S_B + final scalar
__global__ __launch_bounds__(256) void k_final(const float* __restrict__ ws,
                                               float* __restrict__ out) {
    int t = threadIdx.x, w = t >> 6, l = t & 63;
    float csum = ws[WS_CSP + t];
    float cen  = ws[WS_CEPN + t];
    float ced  = ws[WS_CEPD + t];
    float gsum = 0, gmin = 1e30f, vf = 0, vc = 0, tp = 0;
    if (t < 64) {
        tp = ws[WS_TP + t];
        for (int b = 0; b < 64; ++b) {
            vf += ws[WS_VF + b * 64 + t];
            vc += ws[WS_VC + b * 64 + t];
        }
    }
    if (t < 128) { gsum = ws[WS_GS + t]; gmin = ws[WS_GM + t]; }
    float mu_d = vf * (1.0f / (float)N_);
    float vmu  = vc * mu_d;
    float mumu = mu_d * mu_d;
    #pragma unroll
    for (int m = 32; m >= 1; m >>= 1) {
        csum += __shfl_xor(csum, m, 64);
        cen  += __shfl_xor(cen, m, 64);
        ced  += __shfl_xor(ced, m, 64);
        gsum += __shfl_xor(gsum, m, 64);
        gmin = fminf(gmin, __shfl_xor(gmin, m, 64));
        vmu  += __shfl_xor(vmu, m, 64);
        mumu += __shfl_xor(mumu, m, 64);
        tp   += __shfl_xor(tp, m, 64);
    }
    __shared__ float red[4][8];
    if (l == 0) {
        red[w][0] = csum; red[w][1] = cen; red[w][2] = ced; red[w][3] = gsum;
        red[w][4] = gmin; red[w][5] = vmu; red[w][6] = mumu; red[w][7] = tp;
    }
    __syncthreads();
    if (t == 0) {
        float CSM = red[0][0] + red[1][0] + red[2][0] + red[3][0];
        float CEN = red[0][1] + red[1][1] + red[2][1] + red[3][1];
        float CED = red[0][2] + red[1][2] + red[2][2] + red[3][2];
        float GSM = red[0][3] + red[1][3] + red[2][3] + red[3][3];
        float GMN = fminf(fminf(red[0][4], red[1][4]), fminf(red[2][4], red[3][4]));
        float VMU = red[0][5] + red[1][5] + red[2][5] + red[3][5];
        float MUMU = red[0][6] + red[1][6] + red[2][6] + red[3][6];
        float T   = red[0][7] + red[1][7] + red[2][7] + red[3][7];
        float SW = 2.0f * (float)N_ - 2.0f * T;
        float SB = (float)N_ - 2.0f * VMU + (float)N_ * MUMU;
        float intra = SW / (float)N_;
        float fisher = SB / (SW + 1e-6f);
        float ce = CEN / CED;
        float contrast = -(CSM / (float)N_);
        float inter_mean = GSM / (float)(NC_ * (NC_ - 1));
        float reg = intra + 0.1f / (inter_mean + 1e-6f)
                  + 0.05f / (GMN + 1e-6f) + 0.1f / (fisher + 1e-6f);
        out[0] = ce + contrast + reg;
    }
}

extern "C" void kernel_launch(void* const* d_in, const int* in_sizes, int n_in,
                              void* d_out, int out_size, void* d_ws, size_t ws_size,
                              hipStream_t stream) {
    const float* feats        = (const float*)d_in[0];
    const float* logits       = (const float*)d_in[1];
    const int*   labels       = (const int*)d_in[2];
    const float* C            = (const float*)d_in[3];
    const float* queue        = (const float*)d_in[4];
    const float* log_prior    = (const float*)d_in[5];
    const float* class_weight = (const float*)d_in[6];
    float* ws  = (float*)d_ws;
    float* out = (float*)d_out;
    ushort* Bbf = (ushort*)(ws + WS_BBF);

    hipLaunchKernelGGL(k_prep,  dim3(2058),   dim3(256), 0, stream,
                       feats, C, queue, ws + WS_F, ws + WS_CENT, Bbf);
    hipLaunchKernelGGL(k_mega,  dim3(64, 25), dim3(256), 0, stream,
                       Bbf, logits, labels, log_prior, class_weight,
                       ws + WS_F, ws + WS_CENT, ws);
    hipLaunchKernelGGL(k_red,   dim3(256),    dim3(256), 0, stream, ws);
    hipLaunchKernelGGL(k_final, dim3(1),      dim3(256), 0, stream, ws, out);
}